// Round 1
// baseline (1475.693 us; speedup 1.0000x reference)
//
#include <hip/hip_runtime.h>
#include <math.h>

#define BB 2
#define CIN 3
#define IMGD 128
#define HID 64
#define HEADS 4
#define DIM 16
#define PP 64
#define SS 4096
#define NCLS 2
#define EPSV 1e-5f

// ws layout in floats
#define Y_OFF    0
#define STAT_OFF 2097152   // 64 sum + 64 sumsq
#define ACC_OFF  2097280   // B*HEADS*DIM = 128
#define T_OFF    2097408   // 8192 x 64
#define Q_OFF    2621696
#define K_OFF    3145984
#define V_OFF    3670272

// ---------------- Kernel 1: conv3x3 + bias + BN stats ----------------
__global__ __launch_bounds__(256) void k_conv(const float* __restrict__ x,
                                              const float* __restrict__ cw,
                                              const float* __restrict__ cb,
                                              float* __restrict__ y,
                                              float* __restrict__ stats) {
    int blk = blockIdx.x;
    int c = blk & 63, b = blk >> 6;
    float w[27];
#pragma unroll
    for (int i = 0; i < 27; ++i) w[i] = cw[c * 27 + i];
    float bias = cb[c];
    const float* xb = x + b * CIN * IMGD * IMGD;
    float* yb = y + (b * HID + c) * IMGD * IMGD;
    float s1 = 0.f, s2 = 0.f;
    for (int pix = threadIdx.x; pix < IMGD * IMGD; pix += 256) {
        int h = pix >> 7, ww = pix & 127;
        float acc = bias;
#pragma unroll
        for (int ci = 0; ci < 3; ++ci) {
            const float* xc = xb + ci * IMGD * IMGD;
#pragma unroll
            for (int kh = 0; kh < 3; ++kh) {
                int hh = h + kh - 1;
                if (hh < 0 || hh >= IMGD) continue;
#pragma unroll
                for (int kw = 0; kw < 3; ++kw) {
                    int w2 = ww + kw - 1;
                    if (w2 < 0 || w2 >= IMGD) continue;
                    acc += xc[hh * IMGD + w2] * w[ci * 9 + kh * 3 + kw];
                }
            }
        }
        yb[pix] = acc;
        s1 += acc;
        s2 += acc * acc;
    }
    __shared__ float r1[256], r2[256];
    r1[threadIdx.x] = s1;
    r2[threadIdx.x] = s2;
    __syncthreads();
    for (int off = 128; off > 0; off >>= 1) {
        if (threadIdx.x < (unsigned)off) {
            r1[threadIdx.x] += r1[threadIdx.x + off];
            r2[threadIdx.x] += r2[threadIdx.x + off];
        }
        __syncthreads();
    }
    if (threadIdx.x == 0) {
        atomicAdd(&stats[c], r1[0]);
        atomicAdd(&stats[64 + c], r2[0]);
    }
}

// ---------------- Kernel 2: BN + ReLU + 2x2 maxpool -> t (B*S, 64) ----------------
__global__ __launch_bounds__(256) void k_bnpool(const float* __restrict__ y,
                                                const float* __restrict__ stats,
                                                const float* __restrict__ gamma,
                                                const float* __restrict__ beta,
                                                float* __restrict__ t) {
    int b = blockIdx.x >> 6;
    int ph = blockIdx.x & 63;
    __shared__ float lds[64][65];
    const float invN = 1.f / (BB * IMGD * IMGD);
    for (int idx = threadIdx.x; idx < 4096; idx += 256) {
        int c = idx >> 6, pw = idx & 63;
        float mu = stats[c] * invN;
        float var = stats[64 + c] * invN - mu * mu;
        float sc = rsqrtf(var + EPSV) * gamma[c];
        float sh = beta[c] - mu * sc;
        const float* yp = y + ((b * HID + c) * IMGD + 2 * ph) * IMGD + 2 * pw;
        float v0 = yp[0] * sc + sh;
        float v1 = yp[1] * sc + sh;
        float v2 = yp[IMGD] * sc + sh;
        float v3 = yp[IMGD + 1] * sc + sh;
        float m = fmaxf(fmaxf(v0, v1), fmaxf(v2, v3));
        lds[c][pw] = fmaxf(m, 0.f);
    }
    __syncthreads();
    for (int idx = threadIdx.x; idx < 4096; idx += 256) {
        int pw = idx >> 6, c = idx & 63;
        t[((size_t)b * SS + ph * 64 + pw) * 64 + c] = lds[c][pw];
    }
}

// ---------------- Kernel 3: qkv = t @ qkv_w.T + b, scatter to (b,h,s,d) ----------------
__global__ __launch_bounds__(256) void k_qkv(const float* __restrict__ t,
                                             const float* __restrict__ qw,
                                             const float* __restrict__ qb,
                                             float* __restrict__ q,
                                             float* __restrict__ k,
                                             float* __restrict__ v) {
    __shared__ float lt[64][65];
    int m0 = blockIdx.x * 64;
    for (int idx = threadIdx.x; idx < 4096; idx += 256) {
        int r = idx >> 6, kk = idx & 63;
        lt[r][kk] = t[(size_t)(m0 + r) * 64 + kk];
    }
    __syncthreads();
    for (int idx = threadIdx.x; idx < 64 * 192; idx += 256) {
        int ml = idx & 63, n = idx >> 6;
        const float* wr = qw + n * 64;
        float acc = qb[n];
#pragma unroll
        for (int kk = 0; kk < 64; ++kk) acc += lt[ml][kk] * wr[kk];
        int mg = m0 + ml;
        int b = mg >> 12, s = mg & 4095;
        int which = n >> 6, hh = (n >> 4) & 3, d = n & 15;
        float* dst = (which == 0) ? q : ((which == 1) ? k : v);
        dst[(((size_t)(b * HEADS + hh) * SS) + s) * DIM + d] = acc;
    }
}

// ---------------- Kernel 4: flash attention + rel-pos bias + mean-over-q accumulate ----------------
__global__ __launch_bounds__(256) void k_attn(const float* __restrict__ qbuf,
                                              const float* __restrict__ kbuf,
                                              const float* __restrict__ vbuf,
                                              const float* __restrict__ rph,
                                              const float* __restrict__ rpw,
                                              float* __restrict__ acc_out) {
    int bh = blockIdx.x >> 4;
    int qi = (blockIdx.x & 15) * 256 + threadIdx.x;
    int hq = qi >> 6, wq = qi & 63;

    float4 qr[4];
    const float4* qp = (const float4*)(qbuf + ((size_t)bh * SS + qi) * DIM);
    qr[0] = qp[0]; qr[1] = qp[1]; qr[2] = qp[2]; qr[3] = qp[3];
    const float* qf = (const float*)qr;

    // per-thread rel_w row (w_k = 0..63), kept in registers
    float rw[64];
#pragma unroll
    for (int wk = 0; wk < 64; ++wk) {
        const float4* rp = (const float4*)(rpw + (wq - wk + 63) * DIM);
        float4 r0 = rp[0], r1 = rp[1], r2 = rp[2], r3 = rp[3];
        float sacc = qf[0]*r0.x + qf[1]*r0.y + qf[2]*r0.z + qf[3]*r0.w
                   + qf[4]*r1.x + qf[5]*r1.y + qf[6]*r1.z + qf[7]*r1.w
                   + qf[8]*r2.x + qf[9]*r2.y + qf[10]*r2.z + qf[11]*r2.w
                   + qf[12]*r3.x + qf[13]*r3.y + qf[14]*r3.z + qf[15]*r3.w;
        rw[wk] = sacc;
    }

    __shared__ float4 Kl[64][4];
    __shared__ float4 Vl[64][4];
    float l = 0.f;
    float o[16];
#pragma unroll
    for (int d = 0; d < 16; ++d) o[d] = 0.f;

    const float4* kg = (const float4*)(kbuf + (size_t)bh * SS * DIM);
    const float4* vg = (const float4*)(vbuf + (size_t)bh * SS * DIM);

    for (int hk = 0; hk < 64; ++hk) {
        __syncthreads();
        {
            int j = threadIdx.x >> 2, vv = threadIdx.x & 3;
            Kl[j][vv] = kg[(size_t)(hk * 64 + j) * 4 + vv];
            Vl[j][vv] = vg[(size_t)(hk * 64 + j) * 4 + vv];
        }
        __syncthreads();
        const float4* rp = (const float4*)(rph + (hq - hk + 63) * DIM);
        float4 r0 = rp[0], r1 = rp[1], r2 = rp[2], r3 = rp[3];
        float rh = qf[0]*r0.x + qf[1]*r0.y + qf[2]*r0.z + qf[3]*r0.w
                 + qf[4]*r1.x + qf[5]*r1.y + qf[6]*r1.z + qf[7]*r1.w
                 + qf[8]*r2.x + qf[9]*r2.y + qf[10]*r2.z + qf[11]*r2.w
                 + qf[12]*r3.x + qf[13]*r3.y + qf[14]*r3.z + qf[15]*r3.w;
#pragma unroll
        for (int j = 0; j < 64; ++j) {
            float4 k0 = Kl[j][0], k1 = Kl[j][1], k2 = Kl[j][2], k3 = Kl[j][3];
            float s = qf[0]*k0.x + qf[1]*k0.y + qf[2]*k0.z + qf[3]*k0.w
                    + qf[4]*k1.x + qf[5]*k1.y + qf[6]*k1.z + qf[7]*k1.w
                    + qf[8]*k2.x + qf[9]*k2.y + qf[10]*k2.z + qf[11]*k2.w
                    + qf[12]*k3.x + qf[13]*k3.y + qf[14]*k3.z + qf[15]*k3.w;
            s = s * 0.25f + rh + rw[j];
            float p = __expf(s);
            l += p;
            float4 v0 = Vl[j][0], v1 = Vl[j][1], v2 = Vl[j][2], v3 = Vl[j][3];
            o[0]  += p * v0.x; o[1]  += p * v0.y; o[2]  += p * v0.z; o[3]  += p * v0.w;
            o[4]  += p * v1.x; o[5]  += p * v1.y; o[6]  += p * v1.z; o[7]  += p * v1.w;
            o[8]  += p * v2.x; o[9]  += p * v2.y; o[10] += p * v2.z; o[11] += p * v2.w;
            o[12] += p * v3.x; o[13] += p * v3.y; o[14] += p * v3.z; o[15] += p * v3.w;
        }
    }
    float inv = 1.f / l;
#pragma unroll
    for (int d = 0; d < 16; ++d) {
        float val = o[d] * inv;
        val += __shfl_down(val, 32);
        val += __shfl_down(val, 16);
        val += __shfl_down(val, 8);
        val += __shfl_down(val, 4);
        val += __shfl_down(val, 2);
        val += __shfl_down(val, 1);
        if ((threadIdx.x & 63) == 0) atomicAdd(&acc_out[bh * DIM + d], val);
    }
}

// ---------------- Kernel 5: mean + out_proj + fc ----------------
__global__ __launch_bounds__(128) void k_head(const float* __restrict__ acc,
                                              const float* __restrict__ ow,
                                              const float* __restrict__ ob,
                                              const float* __restrict__ fw,
                                              const float* __restrict__ fb,
                                              float* __restrict__ out) {
    __shared__ float feat[2][64];
    int tid = threadIdx.x;
    int b = tid >> 6, c = tid & 63;
    float f2 = ob[c];
    const float invS = 1.f / (float)SS;
#pragma unroll
    for (int cc = 0; cc < 64; ++cc)
        f2 += (acc[b * 64 + cc] * invS) * ow[c * 64 + cc];
    feat[b][c] = f2;
    __syncthreads();
    if (tid < BB * NCLS) {
        int bb = tid >> 1, n = tid & 1;
        float r = fb[n];
#pragma unroll
        for (int cc = 0; cc < 64; ++cc) r += feat[bb][cc] * fw[n * 64 + cc];
        out[bb * NCLS + n] = r;
    }
}

extern "C" void kernel_launch(void* const* d_in, const int* in_sizes, int n_in,
                              void* d_out, int out_size, void* d_ws, size_t ws_size,
                              hipStream_t stream) {
    const float* x      = (const float*)d_in[0];
    const float* conv_w = (const float*)d_in[1];
    const float* conv_b = (const float*)d_in[2];
    const float* bn_g   = (const float*)d_in[3];
    const float* bn_b   = (const float*)d_in[4];
    const float* qkv_w  = (const float*)d_in[5];
    const float* qkv_b  = (const float*)d_in[6];
    const float* rph    = (const float*)d_in[7];
    const float* rpw    = (const float*)d_in[8];
    const float* out_w  = (const float*)d_in[9];
    const float* out_b  = (const float*)d_in[10];
    const float* fc_w   = (const float*)d_in[11];
    const float* fc_b   = (const float*)d_in[12];

    float* ws    = (float*)d_ws;
    float* y     = ws + Y_OFF;
    float* stats = ws + STAT_OFF;
    float* accb  = ws + ACC_OFF;
    float* t     = ws + T_OFF;
    float* q     = ws + Q_OFF;
    float* k     = ws + K_OFF;
    float* v     = ws + V_OFF;

    // zero stats (128) + attention accumulator (128)
    hipMemsetAsync(stats, 0, 256 * sizeof(float), stream);

    k_conv  <<<BB * HID, 256, 0, stream>>>(x, conv_w, conv_b, y, stats);
    k_bnpool<<<BB * PP, 256, 0, stream>>>(y, stats, bn_g, bn_b, t);
    k_qkv   <<<(BB * SS) / 64, 256, 0, stream>>>(t, qkv_w, qkv_b, q, k, v);
    k_attn  <<<BB * HEADS * (SS / 256), 256, 0, stream>>>(q, k, v, rph, rpw, accb);
    k_head  <<<1, 128, 0, stream>>>(accb, out_w, out_b, fc_w, fc_b, (float*)d_out);
}

// Round 2
// 627.665 us; speedup vs baseline: 2.3511x; 2.3511x over previous
//
#include <hip/hip_runtime.h>
#include <math.h>

#define BB 2
#define CIN 3
#define IMGD 128
#define HID 64
#define HEADS 4
#define DIM 16
#define PP 64
#define SS 4096
#define NCLS 2
#define EPSV 1e-5f
#define NKS 8            // key chunks per (bh, qtile)
#define NQ  (BB * HEADS * SS)   // 32768 total queries

// ws layout in floats
#define Y_OFF    0         // conv output, 2,097,152 floats; reused for oq/lq after bnpool
#define OQ_OFF   0         // planar [16][32768] = 524,288 floats (overlaps dead y)
#define LQ_OFF   524288    // 32,768 floats
#define STAT_OFF 2097152   // 64 sum + 64 sumsq
#define ACC_OFF  2097280   // B*HEADS*DIM = 128
#define T_OFF    2097408   // 8192 x 64
#define Q_OFF    2621696
#define K_OFF    3145984
#define V_OFF    3670272

__device__ __forceinline__ float dot16(const float* qf, float4 a0, float4 a1,
                                       float4 a2, float4 a3) {
    float s0 = qf[0] * a0.x + qf[1] * a0.y + qf[2] * a0.z + qf[3] * a0.w;
    float s1 = qf[4] * a1.x + qf[5] * a1.y + qf[6] * a1.z + qf[7] * a1.w;
    float s2 = qf[8] * a2.x + qf[9] * a2.y + qf[10] * a2.z + qf[11] * a2.w;
    float s3 = qf[12] * a3.x + qf[13] * a3.y + qf[14] * a3.z + qf[15] * a3.w;
    return (s0 + s1) + (s2 + s3);
}

// ---------------- Kernel 1: conv3x3 + bias + BN stats (512 blocks) ----------------
__global__ __launch_bounds__(256) void k_conv(const float* __restrict__ x,
                                              const float* __restrict__ cw,
                                              const float* __restrict__ cb,
                                              float* __restrict__ y,
                                              float* __restrict__ stats) {
    int blk = blockIdx.x;
    int strip = blk & 3, c = (blk >> 2) & 63, b = blk >> 8;
    float w[27];
#pragma unroll
    for (int i = 0; i < 27; ++i) w[i] = cw[c * 27 + i];
    float bias = cb[c];
    const float* xb = x + b * CIN * IMGD * IMGD;
    float* yb = y + (b * HID + c) * IMGD * IMGD;
    float s1 = 0.f, s2 = 0.f;
    int base = strip * 4096;
#pragma unroll 4
    for (int ii = 0; ii < 16; ++ii) {
        int pix = base + ii * 256 + threadIdx.x;
        int h = pix >> 7, ww = pix & 127;
        float acc;
        if (h > 0 && h < 127 && ww > 0 && ww < 127) {
            float a0 = bias, a1 = 0.f, a2 = 0.f;
#pragma unroll
            for (int kh = 0; kh < 3; ++kh) {
#pragma unroll
                for (int kw = 0; kw < 3; ++kw) {
                    int off = (h + kh - 1) * IMGD + ww + kw - 1;
                    a0 += xb[off] * w[kh * 3 + kw];
                    a1 += xb[IMGD * IMGD + off] * w[9 + kh * 3 + kw];
                    a2 += xb[2 * IMGD * IMGD + off] * w[18 + kh * 3 + kw];
                }
            }
            acc = a0 + (a1 + a2);
        } else {
            acc = bias;
#pragma unroll
            for (int ci = 0; ci < 3; ++ci) {
                const float* xc = xb + ci * IMGD * IMGD;
#pragma unroll
                for (int kh = 0; kh < 3; ++kh) {
                    int hh = h + kh - 1;
                    if (hh < 0 || hh >= IMGD) continue;
#pragma unroll
                    for (int kw = 0; kw < 3; ++kw) {
                        int w2 = ww + kw - 1;
                        if (w2 < 0 || w2 >= IMGD) continue;
                        acc += xc[hh * IMGD + w2] * w[ci * 9 + kh * 3 + kw];
                    }
                }
            }
        }
        yb[pix] = acc;
        s1 += acc;
        s2 += acc * acc;
    }
    __shared__ float r1[256], r2[256];
    r1[threadIdx.x] = s1;
    r2[threadIdx.x] = s2;
    __syncthreads();
    for (int off = 128; off > 0; off >>= 1) {
        if (threadIdx.x < (unsigned)off) {
            r1[threadIdx.x] += r1[threadIdx.x + off];
            r2[threadIdx.x] += r2[threadIdx.x + off];
        }
        __syncthreads();
    }
    if (threadIdx.x == 0) {
        atomicAdd(&stats[c], r1[0]);
        atomicAdd(&stats[64 + c], r2[0]);
    }
}

// ---------------- Kernel 2: BN + ReLU + 2x2 maxpool -> t (B*S, 64) ----------------
__global__ __launch_bounds__(256) void k_bnpool(const float* __restrict__ y,
                                                const float* __restrict__ stats,
                                                const float* __restrict__ gamma,
                                                const float* __restrict__ beta,
                                                float* __restrict__ t) {
    int b = blockIdx.x >> 6;
    int ph = blockIdx.x & 63;
    __shared__ float lds[64][65];
    const float invN = 1.f / (BB * IMGD * IMGD);
    for (int idx = threadIdx.x; idx < 4096; idx += 256) {
        int c = idx >> 6, pw = idx & 63;
        float mu = stats[c] * invN;
        float var = stats[64 + c] * invN - mu * mu;
        float sc = rsqrtf(var + EPSV) * gamma[c];
        float sh = beta[c] - mu * sc;
        const float* yp = y + ((b * HID + c) * IMGD + 2 * ph) * IMGD + 2 * pw;
        float v0 = yp[0] * sc + sh;
        float v1 = yp[1] * sc + sh;
        float v2 = yp[IMGD] * sc + sh;
        float v3 = yp[IMGD + 1] * sc + sh;
        float m = fmaxf(fmaxf(v0, v1), fmaxf(v2, v3));
        lds[c][pw] = fmaxf(m, 0.f);
    }
    __syncthreads();
    for (int idx = threadIdx.x; idx < 4096; idx += 256) {
        int pw = idx >> 6, c = idx & 63;
        t[((size_t)b * SS + ph * 64 + pw) * 64 + c] = lds[c][pw];
    }
}

// ---------------- Kernel 3: qkv (256 blocks, 32-row tiles) ----------------
__global__ __launch_bounds__(256) void k_qkv(const float* __restrict__ t,
                                             const float* __restrict__ qw,
                                             const float* __restrict__ qb,
                                             float* __restrict__ q,
                                             float* __restrict__ k,
                                             float* __restrict__ v) {
    __shared__ float lt[32][65];
    int m0 = blockIdx.x * 32;
    for (int idx = threadIdx.x; idx < 2048; idx += 256) {
        int r = idx >> 6, kk = idx & 63;
        lt[r][kk] = t[(size_t)(m0 + r) * 64 + kk];
    }
    __syncthreads();
    for (int idx = threadIdx.x; idx < 32 * 192; idx += 256) {
        int ml = idx & 31, n = idx >> 5;
        const float4* wr4 = (const float4*)(qw + n * 64);
        float c0 = 0.f, c1 = 0.f, c2 = 0.f, c3 = 0.f;
#pragma unroll
        for (int kk = 0; kk < 16; ++kk) {
            float4 wv = wr4[kk];
            c0 += lt[ml][4 * kk + 0] * wv.x;
            c1 += lt[ml][4 * kk + 1] * wv.y;
            c2 += lt[ml][4 * kk + 2] * wv.z;
            c3 += lt[ml][4 * kk + 3] * wv.w;
        }
        float acc = qb[n] + ((c0 + c1) + (c2 + c3));
        int mg = m0 + ml;
        int b = mg >> 12, s = mg & 4095;
        int which = n >> 6, hh = (n >> 4) & 3, d = n & 15;
        float* dst = (which == 0) ? q : ((which == 1) ? k : v);
        dst[(((size_t)(b * HEADS + hh) * SS) + s) * DIM + d] = acc;
    }
}

// ---------------- Kernel 4: key-split flash attention, partial (o,l) atomics ----------------
__global__ __launch_bounds__(256) void k_attn(const float* __restrict__ qbuf,
                                              const float* __restrict__ kbuf,
                                              const float* __restrict__ vbuf,
                                              const float* __restrict__ rph,
                                              const float* __restrict__ rpw,
                                              float* __restrict__ oq,
                                              float* __restrict__ lq) {
    int blk = blockIdx.x;
    int qt = blk & 15;
    int kc = (blk >> 4) & 7;
    int bh = blk >> 7;
    int qi = qt * 256 + threadIdx.x;
    int hq = qi >> 6, wq = qi & 63;

    float4 qr[4];
    const float4* qp = (const float4*)(qbuf + ((size_t)bh * SS + qi) * DIM);
    qr[0] = qp[0]; qr[1] = qp[1]; qr[2] = qp[2]; qr[3] = qp[3];
    const float* qf = (const float*)qr;

    // per-thread rel_w row (w_k = 0..63) in registers
    float rw[64];
#pragma unroll
    for (int wk = 0; wk < 64; ++wk) {
        const float4* rp = (const float4*)(rpw + (wq - wk + 63) * DIM);
        rw[wk] = dot16(qf, rp[0], rp[1], rp[2], rp[3]);
    }

    __shared__ float4 Kl[64][4];
    __shared__ float4 Vl[64][4];
    float l = 0.f;
    float o[16];
#pragma unroll
    for (int d = 0; d < 16; ++d) o[d] = 0.f;

    const float4* kg = (const float4*)(kbuf + (size_t)bh * SS * DIM);
    const float4* vg = (const float4*)(vbuf + (size_t)bh * SS * DIM);

    for (int hk = kc * 8; hk < kc * 8 + 8; ++hk) {
        __syncthreads();
        {
            int j = threadIdx.x >> 2, vv = threadIdx.x & 3;
            Kl[j][vv] = kg[(size_t)(hk * 64 + j) * 4 + vv];
            Vl[j][vv] = vg[(size_t)(hk * 64 + j) * 4 + vv];
        }
        __syncthreads();
        const float4* rp = (const float4*)(rph + (hq - hk + 63) * DIM);
        float rh = dot16(qf, rp[0], rp[1], rp[2], rp[3]);
#pragma unroll
        for (int j = 0; j < 64; ++j) {
            float s = dot16(qf, Kl[j][0], Kl[j][1], Kl[j][2], Kl[j][3]);
            s = s * 0.25f + rh + rw[j];
            float p = __expf(s);
            l += p;
            float4 v0 = Vl[j][0], v1 = Vl[j][1], v2 = Vl[j][2], v3 = Vl[j][3];
            o[0]  += p * v0.x; o[1]  += p * v0.y; o[2]  += p * v0.z; o[3]  += p * v0.w;
            o[4]  += p * v1.x; o[5]  += p * v1.y; o[6]  += p * v1.z; o[7]  += p * v1.w;
            o[8]  += p * v2.x; o[9]  += p * v2.y; o[10] += p * v2.z; o[11] += p * v2.w;
            o[12] += p * v3.x; o[13] += p * v3.y; o[14] += p * v3.z; o[15] += p * v3.w;
        }
    }
    int qg = bh * SS + qi;   // 0..32767
    atomicAdd(&lq[qg], l);
#pragma unroll
    for (int d = 0; d < 16; ++d)
        atomicAdd(&oq[d * NQ + qg], o[d]);
}

// ---------------- Kernel 5: per-query normalize + mean-over-q reduce ----------------
__global__ __launch_bounds__(256) void k_red(const float* __restrict__ oq,
                                             const float* __restrict__ lq,
                                             float* __restrict__ acc) {
    int qg = blockIdx.x * 256 + threadIdx.x;   // 0..32767
    int bh = qg >> 12;
    float inv = 1.f / lq[qg];
#pragma unroll
    for (int d = 0; d < 16; ++d) {
        float val = oq[d * NQ + qg] * inv;
        val += __shfl_down(val, 32);
        val += __shfl_down(val, 16);
        val += __shfl_down(val, 8);
        val += __shfl_down(val, 4);
        val += __shfl_down(val, 2);
        val += __shfl_down(val, 1);
        if ((threadIdx.x & 63) == 0) atomicAdd(&acc[bh * DIM + d], val);
    }
}

// ---------------- Kernel 6: mean + out_proj + fc ----------------
__global__ __launch_bounds__(128) void k_head(const float* __restrict__ acc,
                                              const float* __restrict__ ow,
                                              const float* __restrict__ ob,
                                              const float* __restrict__ fw,
                                              const float* __restrict__ fb,
                                              float* __restrict__ out) {
    __shared__ float feat[2][64];
    int tid = threadIdx.x;
    int b = tid >> 6, c = tid & 63;
    float f2 = ob[c];
    const float invS = 1.f / (float)SS;
#pragma unroll
    for (int cc = 0; cc < 64; ++cc)
        f2 += (acc[b * 64 + cc] * invS) * ow[c * 64 + cc];
    feat[b][c] = f2;
    __syncthreads();
    if (tid < BB * NCLS) {
        int bb = tid >> 1, n = tid & 1;
        float r = fb[n];
#pragma unroll
        for (int cc = 0; cc < 64; ++cc) r += feat[bb][cc] * fw[n * 64 + cc];
        out[bb * NCLS + n] = r;
    }
}

extern "C" void kernel_launch(void* const* d_in, const int* in_sizes, int n_in,
                              void* d_out, int out_size, void* d_ws, size_t ws_size,
                              hipStream_t stream) {
    const float* x      = (const float*)d_in[0];
    const float* conv_w = (const float*)d_in[1];
    const float* conv_b = (const float*)d_in[2];
    const float* bn_g   = (const float*)d_in[3];
    const float* bn_b   = (const float*)d_in[4];
    const float* qkv_w  = (const float*)d_in[5];
    const float* qkv_b  = (const float*)d_in[6];
    const float* rph    = (const float*)d_in[7];
    const float* rpw    = (const float*)d_in[8];
    const float* out_w  = (const float*)d_in[9];
    const float* out_b  = (const float*)d_in[10];
    const float* fc_w   = (const float*)d_in[11];
    const float* fc_b   = (const float*)d_in[12];

    float* ws    = (float*)d_ws;
    float* y     = ws + Y_OFF;
    float* oq    = ws + OQ_OFF;   // overlaps y (dead after bnpool)
    float* lq    = ws + LQ_OFF;
    float* stats = ws + STAT_OFF;
    float* accb  = ws + ACC_OFF;
    float* t     = ws + T_OFF;
    float* q     = ws + Q_OFF;
    float* k     = ws + K_OFF;
    float* v     = ws + V_OFF;

    // zero stats (128) + attention accumulator (128)
    hipMemsetAsync(stats, 0, 256 * sizeof(float), stream);

    k_conv  <<<BB * HID * 4, 256, 0, stream>>>(x, conv_w, conv_b, y, stats);
    k_bnpool<<<BB * PP, 256, 0, stream>>>(y, stats, bn_g, bn_b, t);
    // y is dead now; zero the oq/lq partial buffers that overlay it
    hipMemsetAsync(oq, 0, (16 * NQ + NQ) * sizeof(float), stream);
    k_qkv   <<<(BB * SS) / 32, 256, 0, stream>>>(t, qkv_w, qkv_b, q, k, v);
    k_attn  <<<BB * HEADS * (SS / 256) * NKS, 256, 0, stream>>>(q, k, v, rph, rpw, oq, lq);
    k_red   <<<NQ / 256, 256, 0, stream>>>(oq, lq, accb);
    k_head  <<<1, 128, 0, stream>>>(accb, out_w, out_b, fc_w, fc_b, (float*)d_out);
}

// Round 3
// 216.863 us; speedup vs baseline: 6.8047x; 2.8943x over previous
//
#include <hip/hip_runtime.h>
#include <math.h>

#define BB 2
#define CIN 3
#define IMGD 128
#define HID 64
#define HEADS 4
#define DIM 16
#define PP 64
#define SS 4096
#define NCLS 2
#define EPSV 1e-5f

// ws layout in floats
#define Y_OFF    0
#define STAT_OFF 2097152   // 64 sum + 64 sumsq
#define ACC_OFF  2097280   // B*HEADS*DIM = 128
#define T_OFF    2097408   // 8192 x 64
#define Q_OFF    2621696
#define K_OFF    3145984
#define V_OFF    3670272

typedef short bf16x8 __attribute__((ext_vector_type(8)));
typedef float f32x4 __attribute__((ext_vector_type(4)));

__device__ __forceinline__ unsigned short f2bf(float f) {
    unsigned int u = __float_as_uint(f);
    u += 0x7FFFu + ((u >> 16) & 1u);
    return (unsigned short)(u >> 16);
}
__device__ __forceinline__ float bf2f(unsigned short h) {
    return __uint_as_float(((unsigned int)h) << 16);
}
__device__ __forceinline__ unsigned int pk2(float lo, float hi) {
    return (unsigned int)f2bf(lo) | ((unsigned int)f2bf(hi) << 16);
}

__device__ __forceinline__ float dot16(const float* qf, float4 a0, float4 a1,
                                       float4 a2, float4 a3) {
    float s0 = qf[0] * a0.x + qf[1] * a0.y + qf[2] * a0.z + qf[3] * a0.w;
    float s1 = qf[4] * a1.x + qf[5] * a1.y + qf[6] * a1.z + qf[7] * a1.w;
    float s2 = qf[8] * a2.x + qf[9] * a2.y + qf[10] * a2.z + qf[11] * a2.w;
    float s3 = qf[12] * a3.x + qf[13] * a3.y + qf[14] * a3.z + qf[15] * a3.w;
    return (s0 + s1) + (s2 + s3);
}

// ---------------- Kernel 1: conv3x3 + bias + BN stats ----------------
__global__ __launch_bounds__(256) void k_conv(const float* __restrict__ x,
                                              const float* __restrict__ cw,
                                              const float* __restrict__ cb,
                                              float* __restrict__ y,
                                              float* __restrict__ stats) {
    int blk = blockIdx.x;
    int strip = blk & 3, c = (blk >> 2) & 63, b = blk >> 8;
    float w[27];
#pragma unroll
    for (int i = 0; i < 27; ++i) w[i] = cw[c * 27 + i];
    float bias = cb[c];
    const float* xb = x + b * CIN * IMGD * IMGD;
    float* yb = y + (b * HID + c) * IMGD * IMGD;
    float s1 = 0.f, s2 = 0.f;
    int base = strip * 4096;
#pragma unroll 4
    for (int ii = 0; ii < 16; ++ii) {
        int pix = base + ii * 256 + threadIdx.x;
        int h = pix >> 7, ww = pix & 127;
        float acc;
        if (h > 0 && h < 127 && ww > 0 && ww < 127) {
            float a0 = bias, a1 = 0.f, a2 = 0.f;
#pragma unroll
            for (int kh = 0; kh < 3; ++kh) {
#pragma unroll
                for (int kw = 0; kw < 3; ++kw) {
                    int off = (h + kh - 1) * IMGD + ww + kw - 1;
                    a0 += xb[off] * w[kh * 3 + kw];
                    a1 += xb[IMGD * IMGD + off] * w[9 + kh * 3 + kw];
                    a2 += xb[2 * IMGD * IMGD + off] * w[18 + kh * 3 + kw];
                }
            }
            acc = a0 + (a1 + a2);
        } else {
            acc = bias;
#pragma unroll
            for (int ci = 0; ci < 3; ++ci) {
                const float* xc = xb + ci * IMGD * IMGD;
#pragma unroll
                for (int kh = 0; kh < 3; ++kh) {
                    int hh = h + kh - 1;
                    if (hh < 0 || hh >= IMGD) continue;
#pragma unroll
                    for (int kw = 0; kw < 3; ++kw) {
                        int w2 = ww + kw - 1;
                        if (w2 < 0 || w2 >= IMGD) continue;
                        acc += xc[hh * IMGD + w2] * w[ci * 9 + kh * 3 + kw];
                    }
                }
            }
        }
        yb[pix] = acc;
        s1 += acc;
        s2 += acc * acc;
    }
    __shared__ float r1[256], r2[256];
    r1[threadIdx.x] = s1;
    r2[threadIdx.x] = s2;
    __syncthreads();
    for (int off = 128; off > 0; off >>= 1) {
        if (threadIdx.x < (unsigned)off) {
            r1[threadIdx.x] += r1[threadIdx.x + off];
            r2[threadIdx.x] += r2[threadIdx.x + off];
        }
        __syncthreads();
    }
    if (threadIdx.x == 0) {
        atomicAdd(&stats[c], r1[0]);
        atomicAdd(&stats[64 + c], r2[0]);
    }
}

// ---------------- Kernel 2: BN + ReLU + 2x2 maxpool -> t (B*S, 64) ----------------
__global__ __launch_bounds__(256) void k_bnpool(const float* __restrict__ y,
                                                const float* __restrict__ stats,
                                                const float* __restrict__ gamma,
                                                const float* __restrict__ beta,
                                                float* __restrict__ t) {
    int b = blockIdx.x >> 6;
    int ph = blockIdx.x & 63;
    __shared__ float lds[64][65];
    const float invN = 1.f / (BB * IMGD * IMGD);
    for (int idx = threadIdx.x; idx < 4096; idx += 256) {
        int c = idx >> 6, pw = idx & 63;
        float mu = stats[c] * invN;
        float var = stats[64 + c] * invN - mu * mu;
        float sc = rsqrtf(var + EPSV) * gamma[c];
        float sh = beta[c] - mu * sc;
        const float* yp = y + ((b * HID + c) * IMGD + 2 * ph) * IMGD + 2 * pw;
        float v0 = yp[0] * sc + sh;
        float v1 = yp[1] * sc + sh;
        float v2 = yp[IMGD] * sc + sh;
        float v3 = yp[IMGD + 1] * sc + sh;
        float m = fmaxf(fmaxf(v0, v1), fmaxf(v2, v3));
        lds[c][pw] = fmaxf(m, 0.f);
    }
    __syncthreads();
    for (int idx = threadIdx.x; idx < 4096; idx += 256) {
        int pw = idx >> 6, c = idx & 63;
        t[((size_t)b * SS + ph * 64 + pw) * 64 + c] = lds[c][pw];
    }
}

// ---------------- Kernel 3: qkv GEMM + scatter ----------------
__global__ __launch_bounds__(256) void k_qkv(const float* __restrict__ t,
                                             const float* __restrict__ qw,
                                             const float* __restrict__ qb,
                                             float* __restrict__ q,
                                             float* __restrict__ k,
                                             float* __restrict__ v) {
    __shared__ float lt[32][65];
    int m0 = blockIdx.x * 32;
    for (int idx = threadIdx.x; idx < 2048; idx += 256) {
        int r = idx >> 6, kk = idx & 63;
        lt[r][kk] = t[(size_t)(m0 + r) * 64 + kk];
    }
    __syncthreads();
    for (int idx = threadIdx.x; idx < 32 * 192; idx += 256) {
        int ml = idx & 31, n = idx >> 5;
        const float4* wr4 = (const float4*)(qw + n * 64);
        float c0 = 0.f, c1 = 0.f, c2 = 0.f, c3 = 0.f;
#pragma unroll
        for (int kk = 0; kk < 16; ++kk) {
            float4 wv = wr4[kk];
            c0 += lt[ml][4 * kk + 0] * wv.x;
            c1 += lt[ml][4 * kk + 1] * wv.y;
            c2 += lt[ml][4 * kk + 2] * wv.z;
            c3 += lt[ml][4 * kk + 3] * wv.w;
        }
        float acc = qb[n] + ((c0 + c1) + (c2 + c3));
        int mg = m0 + ml;
        int b = mg >> 12, s = mg & 4095;
        int which = n >> 6, hh = (n >> 4) & 3, d = n & 15;
        float* dst = (which == 0) ? q : ((which == 1) ? k : v);
        dst[(((size_t)(b * HEADS + hh) * SS) + s) * DIM + d] = acc;
    }
}

// ---------------- Kernel 4: MFMA flash attention ----------------
// block = (bh, hq): 64 queries of one image row. 4 waves x 16 queries.
// LDS offsets in ushorts
#define RELH_O 0        // [64][66] bf16
#define RELW_O 4224     // [64][132] bf16
#define KK_O   12672    // [256][24] bf16
#define VT_O   18816    // [16][264] bf16
#define PB_O   23040    // [4 waves][16][40] bf16
#define RELH_S 66
#define RELW_S 132
#define KK_S   24
#define VT_S   264
#define PB_S   40

__global__ __launch_bounds__(256) void k_attn(const float* __restrict__ qbuf,
                                              const float* __restrict__ kbuf,
                                              const float* __restrict__ vbuf,
                                              const float* __restrict__ rph,
                                              const float* __restrict__ rpw,
                                              float* __restrict__ accb) {
    __shared__ unsigned short sm[25600];
    int bh = blockIdx.x >> 6;
    int hq = blockIdx.x & 63;
    int tid = threadIdx.x;
    int w = tid >> 6, l = tid & 63;
    int m = l & 15, g = l >> 4;

    // stage Rh rows (indexed by hk) and Rw rows (indexed by idx) as f32
    float* rhF = (float*)(sm + VT_O);   // [64][16]
    float* rwF = (float*)(sm + KK_O);   // [127][16]
    for (int i = tid; i < 64 * 16; i += 256) {
        int hk = i >> 4, c = i & 15;
        rhF[i] = rph[(hq + 63 - hk) * 16 + c];
    }
    for (int i = tid; i < 127 * 16; i += 256) rwF[i] = rpw[i];
    __syncthreads();

    // precompute relh[q][hk], relw[q][idx] (bf16, pre-scaled by 1/ln2)
    {
        int qq = tid & 63;       // == wq
        int part = tid >> 6;
        const float4* qp = (const float4*)(qbuf + ((size_t)bh * SS + hq * 64 + qq) * DIM);
        float4 q0 = qp[0], q1 = qp[1], q2 = qp[2], q3 = qp[3];
        float qf[16];
        *(float4*)(qf) = q0; *(float4*)(qf + 4) = q1;
        *(float4*)(qf + 8) = q2; *(float4*)(qf + 12) = q3;
#pragma unroll
        for (int i = 0; i < 16; ++i) {
            int hk = part * 16 + i;
            const float4* rr = (const float4*)(rhF + hk * 16);
            float vv = dot16(qf, rr[0], rr[1], rr[2], rr[3]) * 1.44269504f;
            sm[RELH_O + qq * RELH_S + hk] = f2bf(vv);
        }
#pragma unroll
        for (int i = 0; i < 32; ++i) {
            int idx = part * 32 + i;
            if (idx < 127) {
                const float4* rr = (const float4*)(rwF + idx * 16);
                float vv = dot16(qf, rr[0], rr[1], rr[2], rr[3]) * 1.44269504f;
                sm[RELW_O + qq * RELW_S + idx] = f2bf(vv);
            }
        }
    }

    // Q^T B-frag: lane needs Q[q=m][d = 8g + r], zero for g>=2 (K pad)
    bf16x8 qfrag = (bf16x8)(short)0;
    if (g < 2) {
        const float* qrow = qbuf + ((size_t)bh * SS + hq * 64 + w * 16 + m) * DIM + g * 8;
        float4 a = *(const float4*)(qrow);
        float4 b = *(const float4*)(qrow + 4);
        unsigned int u0 = pk2(a.x, a.y), u1 = pk2(a.z, a.w);
        unsigned int u2 = pk2(b.x, b.y), u3 = pk2(b.z, b.w);
        unsigned int qv[4] = {u0, u1, u2, u3};
        qfrag = *(bf16x8*)qv;
    }

    f32x4 oacc = {0.f, 0.f, 0.f, 0.f};
    float lsum = 0.f;
    const float C1 = 0.25f * 1.44269504f;
    int wq = w * 16 + m;

    for (int ch = 0; ch < 16; ++ch) {
        __syncthreads();
        // stage 256 keys: K -> [key][24] bf16 rows, V -> V^T [16][264] bf16
        {
            size_t key = (size_t)bh * SS + ch * 256 + tid;
            const float4* kp = (const float4*)(kbuf + key * DIM);
            float4 k0 = kp[0], k1 = kp[1], k2 = kp[2], k3 = kp[3];
            uint2* krow = (uint2*)(sm + KK_O + tid * KK_S);
            krow[0] = make_uint2(pk2(k0.x, k0.y), pk2(k0.z, k0.w));
            krow[1] = make_uint2(pk2(k1.x, k1.y), pk2(k1.z, k1.w));
            krow[2] = make_uint2(pk2(k2.x, k2.y), pk2(k2.z, k2.w));
            krow[3] = make_uint2(pk2(k3.x, k3.y), pk2(k3.z, k3.w));
            const float4* vp = (const float4*)(vbuf + key * DIM);
            float4 v0 = vp[0], v1 = vp[1], v2 = vp[2], v3 = vp[3];
            float vv[16];
            *(float4*)(vv) = v0; *(float4*)(vv + 4) = v1;
            *(float4*)(vv + 8) = v2; *(float4*)(vv + 12) = v3;
#pragma unroll
            for (int d = 0; d < 16; ++d)
                sm[VT_O + d * VT_S + tid] = f2bf(vv[d]);
        }
        __syncthreads();

#pragma unroll 2
        for (int g2 = 0; g2 < 8; ++g2) {
            int kk0 = g2 * 32;
            int hk = ch * 4 + (g2 >> 1);
            int wk0 = (g2 & 1) * 32;
            float rh = bf2f(sm[RELH_O + wq * RELH_S + hk]);
            unsigned short* prow = sm + PB_O + w * 640 + m * PB_S;
#pragma unroll
            for (int t2 = 0; t2 < 2; ++t2) {
                bf16x8 kf = (bf16x8)(short)0;
                if (g < 2)
                    kf = *(bf16x8*)(sm + KK_O + (kk0 + t2 * 16 + m) * KK_S + g * 8);
                f32x4 st = __builtin_amdgcn_mfma_f32_16x16x32_bf16(
                    kf, qfrag, (f32x4){0.f, 0.f, 0.f, 0.f}, 0, 0, 0);
                float p0, p1, p2, p3;
                {
                    int ib = wq - (wk0 + t2 * 16 + 4 * g) + 63;
                    float rw0 = bf2f(sm[RELW_O + wq * RELW_S + ib]);
                    float rw1 = bf2f(sm[RELW_O + wq * RELW_S + ib - 1]);
                    float rw2 = bf2f(sm[RELW_O + wq * RELW_S + ib - 2]);
                    float rw3 = bf2f(sm[RELW_O + wq * RELW_S + ib - 3]);
                    p0 = __builtin_exp2f(fmaf(st[0], C1, rh + rw0));
                    p1 = __builtin_exp2f(fmaf(st[1], C1, rh + rw1));
                    p2 = __builtin_exp2f(fmaf(st[2], C1, rh + rw2));
                    p3 = __builtin_exp2f(fmaf(st[3], C1, rh + rw3));
                }
                lsum += (p0 + p1) + (p2 + p3);
                *(uint2*)(prow + t2 * 16 + 4 * g) =
                    make_uint2(pk2(p0, p1), pk2(p2, p3));
            }
            // PV: O^T += V^T (16d x 32k) * P^T (32k x 16q)
            bf16x8 pf = *(bf16x8*)(prow + 8 * g);
            bf16x8 vf = *(bf16x8*)(sm + VT_O + m * VT_S + kk0 + 8 * g);
            oacc = __builtin_amdgcn_mfma_f32_16x16x32_bf16(vf, pf, oacc, 0, 0, 0);
        }
    }

    // reduce l across the 4 lane-groups (same q)
    float t1 = lsum + __shfl_xor(lsum, 16);
    float lf = t1 + __shfl_xor(t1, 32);
    float linv = 1.f / lf;
#pragma unroll
    for (int r = 0; r < 4; ++r) {
        float val = oacc[r] * linv;   // O[q=m][d=4g+r]
        val += __shfl_xor(val, 1);
        val += __shfl_xor(val, 2);
        val += __shfl_xor(val, 4);
        val += __shfl_xor(val, 8);
        if (m == 0) atomicAdd(&accb[bh * DIM + 4 * g + r], val);
    }
}

// ---------------- Kernel 5: mean + out_proj + fc ----------------
__global__ __launch_bounds__(128) void k_head(const float* __restrict__ acc,
                                              const float* __restrict__ ow,
                                              const float* __restrict__ ob,
                                              const float* __restrict__ fw,
                                              const float* __restrict__ fb,
                                              float* __restrict__ out) {
    __shared__ float feat[2][64];
    int tid = threadIdx.x;
    int b = tid >> 6, c = tid & 63;
    float f2 = ob[c];
    const float invS = 1.f / (float)SS;
#pragma unroll
    for (int cc = 0; cc < 64; ++cc)
        f2 += (acc[b * 64 + cc] * invS) * ow[c * 64 + cc];
    feat[b][c] = f2;
    __syncthreads();
    if (tid < BB * NCLS) {
        int bb = tid >> 1, n = tid & 1;
        float r = fb[n];
#pragma unroll
        for (int cc = 0; cc < 64; ++cc) r += feat[bb][cc] * fw[n * 64 + cc];
        out[bb * NCLS + n] = r;
    }
}

extern "C" void kernel_launch(void* const* d_in, const int* in_sizes, int n_in,
                              void* d_out, int out_size, void* d_ws, size_t ws_size,
                              hipStream_t stream) {
    const float* x      = (const float*)d_in[0];
    const float* conv_w = (const float*)d_in[1];
    const float* conv_b = (const float*)d_in[2];
    const float* bn_g   = (const float*)d_in[3];
    const float* bn_b   = (const float*)d_in[4];
    const float* qkv_w  = (const float*)d_in[5];
    const float* qkv_b  = (const float*)d_in[6];
    const float* rph    = (const float*)d_in[7];
    const float* rpw    = (const float*)d_in[8];
    const float* out_w  = (const float*)d_in[9];
    const float* out_b  = (const float*)d_in[10];
    const float* fc_w   = (const float*)d_in[11];
    const float* fc_b   = (const float*)d_in[12];

    float* ws    = (float*)d_ws;
    float* y     = ws + Y_OFF;
    float* stats = ws + STAT_OFF;
    float* accb  = ws + ACC_OFF;
    float* t     = ws + T_OFF;
    float* q     = ws + Q_OFF;
    float* k     = ws + K_OFF;
    float* v     = ws + V_OFF;

    // zero stats (128) + attention accumulator (128)
    hipMemsetAsync(stats, 0, 256 * sizeof(float), stream);

    k_conv  <<<BB * HID * 4, 256, 0, stream>>>(x, conv_w, conv_b, y, stats);
    k_bnpool<<<BB * PP, 256, 0, stream>>>(y, stats, bn_g, bn_b, t);
    k_qkv   <<<(BB * SS) / 32, 256, 0, stream>>>(t, qkv_w, qkv_b, q, k, v);
    k_attn  <<<BB * HEADS * PP, 256, 0, stream>>>(q, k, v, rph, rpw, accb);
    k_head  <<<1, 128, 0, stream>>>(accb, out_w, out_b, fc_w, fc_b, (float*)d_out);
}

// Round 4
// 183.981 us; speedup vs baseline: 8.0209x; 1.1787x over previous
//
#include <hip/hip_runtime.h>
#include <math.h>

#define BB 2
#define CIN 3
#define IMGD 128
#define HID 64
#define HEADS 4
#define DIM 16
#define PP 64
#define SS 4096
#define NCLS 2
#define EPSV 1e-5f
#define NQ 32768

// ws layout in floats (region 0..2097152 = dead conv y, reused after bnpool)
#define Y_OFF    0
#define OQ_OFF   0         // [2][16][NQ] = 1,048,576 floats
#define LQ_OFF   1048576   // [2][NQ] = 65,536
#define KBF_OFF  1114112   // bf16 K [8][4096][16] = 524,288 u16 = 262,144 f32 slots
#define VTB_OFF  1376256   // bf16 V^T [8][16][4096] = 262,144 f32 slots
#define STAT_OFF 2097152   // 64 sum + 64 sumsq
#define ACC_OFF  2097280   // B*HEADS*DIM = 128
#define T_OFF    2097408   // 8192 x 64
#define Q_OFF    2621696   // q f32 (b,h,s,d)

typedef short bf16x8 __attribute__((ext_vector_type(8)));
typedef float f32x4 __attribute__((ext_vector_type(4)));

__device__ __forceinline__ unsigned short f2bf(float f) {
    unsigned int u = __float_as_uint(f);
    u += 0x7FFFu + ((u >> 16) & 1u);
    return (unsigned short)(u >> 16);
}
__device__ __forceinline__ float bf2f(unsigned short h) {
    return __uint_as_float(((unsigned int)h) << 16);
}
__device__ __forceinline__ unsigned int pk2(float lo, float hi) {
    return (unsigned int)f2bf(lo) | ((unsigned int)f2bf(hi) << 16);
}

__device__ __forceinline__ float dot16(const float* qf, float4 a0, float4 a1,
                                       float4 a2, float4 a3) {
    float s0 = qf[0] * a0.x + qf[1] * a0.y + qf[2] * a0.z + qf[3] * a0.w;
    float s1 = qf[4] * a1.x + qf[5] * a1.y + qf[6] * a1.z + qf[7] * a1.w;
    float s2 = qf[8] * a2.x + qf[9] * a2.y + qf[10] * a2.z + qf[11] * a2.w;
    float s3 = qf[12] * a3.x + qf[13] * a3.y + qf[14] * a3.z + qf[15] * a3.w;
    return (s0 + s1) + (s2 + s3);
}

// ---------------- Kernel 1: conv3x3 + bias + BN stats ----------------
__global__ __launch_bounds__(256) void k_conv(const float* __restrict__ x,
                                              const float* __restrict__ cw,
                                              const float* __restrict__ cb,
                                              float* __restrict__ y,
                                              float* __restrict__ stats) {
    int blk = blockIdx.x;
    int strip = blk & 3, c = (blk >> 2) & 63, b = blk >> 8;
    float w[27];
#pragma unroll
    for (int i = 0; i < 27; ++i) w[i] = cw[c * 27 + i];
    float bias = cb[c];
    const float* xb = x + b * CIN * IMGD * IMGD;
    float* yb = y + (b * HID + c) * IMGD * IMGD;
    float s1 = 0.f, s2 = 0.f;
    int base = strip * 4096;
#pragma unroll 4
    for (int ii = 0; ii < 16; ++ii) {
        int pix = base + ii * 256 + threadIdx.x;
        int h = pix >> 7, ww = pix & 127;
        float acc;
        if (h > 0 && h < 127 && ww > 0 && ww < 127) {
            float a0 = bias, a1 = 0.f, a2 = 0.f;
#pragma unroll
            for (int kh = 0; kh < 3; ++kh) {
#pragma unroll
                for (int kw = 0; kw < 3; ++kw) {
                    int off = (h + kh - 1) * IMGD + ww + kw - 1;
                    a0 += xb[off] * w[kh * 3 + kw];
                    a1 += xb[IMGD * IMGD + off] * w[9 + kh * 3 + kw];
                    a2 += xb[2 * IMGD * IMGD + off] * w[18 + kh * 3 + kw];
                }
            }
            acc = a0 + (a1 + a2);
        } else {
            acc = bias;
#pragma unroll
            for (int ci = 0; ci < 3; ++ci) {
                const float* xc = xb + ci * IMGD * IMGD;
#pragma unroll
                for (int kh = 0; kh < 3; ++kh) {
                    int hh = h + kh - 1;
                    if (hh < 0 || hh >= IMGD) continue;
#pragma unroll
                    for (int kw = 0; kw < 3; ++kw) {
                        int w2 = ww + kw - 1;
                        if (w2 < 0 || w2 >= IMGD) continue;
                        acc += xc[hh * IMGD + w2] * w[ci * 9 + kh * 3 + kw];
                    }
                }
            }
        }
        yb[pix] = acc;
        s1 += acc;
        s2 += acc * acc;
    }
    __shared__ float r1[256], r2[256];
    r1[threadIdx.x] = s1;
    r2[threadIdx.x] = s2;
    __syncthreads();
    for (int off = 128; off > 0; off >>= 1) {
        if (threadIdx.x < (unsigned)off) {
            r1[threadIdx.x] += r1[threadIdx.x + off];
            r2[threadIdx.x] += r2[threadIdx.x + off];
        }
        __syncthreads();
    }
    if (threadIdx.x == 0) {
        atomicAdd(&stats[c], r1[0]);
        atomicAdd(&stats[64 + c], r2[0]);
    }
}

// ---------------- Kernel 2: BN + ReLU + 2x2 maxpool -> t (B*S, 64) ----------------
__global__ __launch_bounds__(256) void k_bnpool(const float* __restrict__ y,
                                                const float* __restrict__ stats,
                                                const float* __restrict__ gamma,
                                                const float* __restrict__ beta,
                                                float* __restrict__ t) {
    int b = blockIdx.x >> 6;
    int ph = blockIdx.x & 63;
    __shared__ float lds[64][65];
    const float invN = 1.f / (BB * IMGD * IMGD);
    for (int idx = threadIdx.x; idx < 4096; idx += 256) {
        int c = idx >> 6, pw = idx & 63;
        float mu = stats[c] * invN;
        float var = stats[64 + c] * invN - mu * mu;
        float sc = rsqrtf(var + EPSV) * gamma[c];
        float sh = beta[c] - mu * sc;
        const float* yp = y + ((b * HID + c) * IMGD + 2 * ph) * IMGD + 2 * pw;
        float v0 = yp[0] * sc + sh;
        float v1 = yp[1] * sc + sh;
        float v2 = yp[IMGD] * sc + sh;
        float v3 = yp[IMGD + 1] * sc + sh;
        float m = fmaxf(fmaxf(v0, v1), fmaxf(v2, v3));
        lds[c][pw] = fmaxf(m, 0.f);
    }
    __syncthreads();
    for (int idx = threadIdx.x; idx < 4096; idx += 256) {
        int pw = idx >> 6, c = idx & 63;
        t[((size_t)b * SS + ph * 64 + pw) * 64 + c] = lds[c][pw];
    }
}

// ---------------- Kernel 3: qkv GEMM; q->f32, k->bf16 rows, v->bf16 transposed ----------------
__global__ __launch_bounds__(256) void k_qkv(const float* __restrict__ t,
                                             const float* __restrict__ qw,
                                             const float* __restrict__ qb,
                                             float* __restrict__ q,
                                             unsigned short* __restrict__ kbf,
                                             unsigned short* __restrict__ vT) {
    __shared__ float lt[32][65];
    int m0 = blockIdx.x * 32;
    for (int idx = threadIdx.x; idx < 2048; idx += 256) {
        int r = idx >> 6, kk = idx & 63;
        lt[r][kk] = t[(size_t)(m0 + r) * 64 + kk];
    }
    __syncthreads();
    for (int idx = threadIdx.x; idx < 32 * 192; idx += 256) {
        int ml = idx & 31, n = idx >> 5;
        const float4* wr4 = (const float4*)(qw + n * 64);
        float c0 = 0.f, c1 = 0.f, c2 = 0.f, c3 = 0.f;
#pragma unroll
        for (int kk = 0; kk < 16; ++kk) {
            float4 wv = wr4[kk];
            c0 += lt[ml][4 * kk + 0] * wv.x;
            c1 += lt[ml][4 * kk + 1] * wv.y;
            c2 += lt[ml][4 * kk + 2] * wv.z;
            c3 += lt[ml][4 * kk + 3] * wv.w;
        }
        float acc = qb[n] + ((c0 + c1) + (c2 + c3));
        int mg = m0 + ml;
        int b = mg >> 12, s = mg & 4095;
        int which = n >> 6, hh = (n >> 4) & 3, d = n & 15;
        int bh = b * HEADS + hh;
        if (which == 0)      q[((size_t)bh * SS + s) * DIM + d] = acc;
        else if (which == 1) kbf[((size_t)bh * SS + s) * 16 + d] = f2bf(acc);
        else                 vT[((size_t)bh * 16 + d) * SS + s] = f2bf(acc);
    }
}

// ---------------- Kernel 4: MFMA flash attention, key-split x2 ----------------
// block = (bh, hq, kc): 64 queries x 2048 keys. 4 waves x 16 queries.
// LDS offsets in ushorts (total 19584 u16 = 39168 B -> 4 blocks/CU)
#define RELH_O 0        // [64][36]
#define RELH_S 36
#define RELW_O 2304     // [64][68], direct [wq][wk]
#define RELW_S 68
#define KK_O   6656     // [256][24]
#define KK_S   24
#define VT_O   12800    // [16][264]
#define VT_S   264
#define PB_O   17024    // [4 waves][16][40]
#define PB_S   40

__global__ __launch_bounds__(256, 4) void k_attn(const float* __restrict__ qbuf,
                                                 const unsigned short* __restrict__ kbf,
                                                 const unsigned short* __restrict__ vT,
                                                 const float* __restrict__ rph,
                                                 const float* __restrict__ rpw,
                                                 float* __restrict__ oq,
                                                 float* __restrict__ lq) {
    __shared__ unsigned short sm[19584];
    int blk = blockIdx.x;
    int kc = blk & 1;
    int hq = (blk >> 1) & 63;
    int bh = blk >> 7;
    int tid = threadIdx.x;
    int w = tid >> 6, l = tid & 63;
    int m = l & 15, g = l >> 4;
    int wq = w * 16 + m;

    // issue chunk-0 staging loads early (T14)
    uint4 kreg0, kreg1, vreg0, vreg1;
    int vd = tid >> 4, vc = (tid & 15) * 16;
    {
        int ch = kc * 8;
        const uint4* kp = (const uint4*)(kbf + ((size_t)(bh * SS + ch * 256 + tid)) * 16);
        kreg0 = kp[0]; kreg1 = kp[1];
        const uint4* vp = (const uint4*)(vT + ((size_t)(bh * 16 + vd)) * SS + ch * 256 + vc);
        vreg0 = vp[0]; vreg1 = vp[1];
    }

    // stage Rh (needed half) and Rw rows as f32 into scratch overlays
    float* rhF = (float*)(sm + KK_O);   // [32][16] = 2048 B
    float* rwF = (float*)(sm + VT_O);   // [127][16] = 8128 B
    for (int i = tid; i < 32 * 16; i += 256) {
        int hkl = i >> 4, cc = i & 15;
        rhF[i] = rph[(hq + 63 - kc * 32 - hkl) * 16 + cc];
    }
    for (int i = tid; i < 127 * 16; i += 256) rwF[i] = rpw[i];
    __syncthreads();

    // precompute bias tables (bf16, pre-scaled by log2 e)
    {
        int qq = tid & 63, part = tid >> 6;
        const float4* qp = (const float4*)(qbuf + ((size_t)bh * SS + hq * 64 + qq) * DIM);
        float qf[16];
        *(float4*)(qf) = qp[0]; *(float4*)(qf + 4) = qp[1];
        *(float4*)(qf + 8) = qp[2]; *(float4*)(qf + 12) = qp[3];
#pragma unroll
        for (int i = 0; i < 8; ++i) {
            int hkl = part * 8 + i;
            const float4* rr = (const float4*)(rhF + hkl * 16);
            float vv = dot16(qf, rr[0], rr[1], rr[2], rr[3]) * 1.44269504f;
            sm[RELH_O + qq * RELH_S + hkl] = f2bf(vv);
        }
#pragma unroll
        for (int i = 0; i < 16; ++i) {
            int wk = part * 16 + i;
            const float4* rr = (const float4*)(rwF + (qq - wk + 63) * 16);
            float vv = dot16(qf, rr[0], rr[1], rr[2], rr[3]) * 1.44269504f;
            sm[RELW_O + qq * RELW_S + wk] = f2bf(vv);
        }
    }

    // Q^T B-frag: lane (g<2, m) holds Q[q=wq][d=8g..8g+7] bf16
    bf16x8 qfrag = (bf16x8)(short)0;
    if (g < 2) {
        const float* qrow = qbuf + ((size_t)bh * SS + hq * 64 + wq) * DIM + g * 8;
        float4 a = *(const float4*)(qrow);
        float4 b = *(const float4*)(qrow + 4);
        unsigned int qv[4] = {pk2(a.x, a.y), pk2(a.z, a.w), pk2(b.x, b.y), pk2(b.z, b.w)};
        qfrag = *(bf16x8*)qv;
    }

    f32x4 oacc = {0.f, 0.f, 0.f, 0.f};
    float lsum = 0.f;
    const float C1 = 0.25f * 1.44269504f;

    for (int c = 0; c < 8; ++c) {
        __syncthreads();   // previous compute done / rel-scratch free
        // write staged regs -> LDS
        *(uint4*)(sm + KK_O + tid * KK_S) = kreg0;
        *(uint4*)(sm + KK_O + tid * KK_S + 8) = kreg1;
        *(uint4*)(sm + VT_O + vd * VT_S + vc) = vreg0;
        *(uint4*)(sm + VT_O + vd * VT_S + vc + 8) = vreg1;
        __syncthreads();
        if (c < 7) {   // issue next chunk's loads (hidden under compute)
            int ch = kc * 8 + c + 1;
            const uint4* kp = (const uint4*)(kbf + ((size_t)(bh * SS + ch * 256 + tid)) * 16);
            kreg0 = kp[0]; kreg1 = kp[1];
            const uint4* vp = (const uint4*)(vT + ((size_t)(bh * 16 + vd)) * SS + ch * 256 + vc);
            vreg0 = vp[0]; vreg1 = vp[1];
        }

#pragma unroll 2
        for (int g2 = 0; g2 < 8; ++g2) {
            int kk0 = g2 * 32;
            int hkl = c * 4 + (g2 >> 1);
            float rh = bf2f(sm[RELH_O + wq * RELH_S + hkl]);
            unsigned short* prow = sm + PB_O + w * 640 + m * PB_S;
#pragma unroll
            for (int t2 = 0; t2 < 2; ++t2) {
                bf16x8 kf = (bf16x8)(short)0;
                if (g < 2)
                    kf = *(bf16x8*)(sm + KK_O + (kk0 + t2 * 16 + m) * KK_S + g * 8);
                f32x4 st = __builtin_amdgcn_mfma_f32_16x16x32_bf16(
                    kf, qfrag, (f32x4){0.f, 0.f, 0.f, 0.f}, 0, 0, 0);
                int wk0 = (g2 & 1) * 32 + t2 * 16 + 4 * g;
                uint2 rwp = *(uint2*)(sm + RELW_O + wq * RELW_S + wk0);
                float rw0 = __uint_as_float(rwp.x << 16);
                float rw1 = __uint_as_float(rwp.x & 0xffff0000u);
                float rw2 = __uint_as_float(rwp.y << 16);
                float rw3 = __uint_as_float(rwp.y & 0xffff0000u);
                float p0 = __builtin_exp2f(fmaf(st[0], C1, rh + rw0));
                float p1 = __builtin_exp2f(fmaf(st[1], C1, rh + rw1));
                float p2 = __builtin_exp2f(fmaf(st[2], C1, rh + rw2));
                float p3 = __builtin_exp2f(fmaf(st[3], C1, rh + rw3));
                lsum += (p0 + p1) + (p2 + p3);
                unsigned int u0, u1;
                asm("v_cvt_pk_bf16_f32 %0, %1, %2" : "=v"(u0) : "v"(p0), "v"(p1));
                asm("v_cvt_pk_bf16_f32 %0, %1, %2" : "=v"(u1) : "v"(p2), "v"(p3));
                *(uint2*)(prow + t2 * 16 + 4 * g) = make_uint2(u0, u1);
            }
            // PV: O^T += V^T (16d x 32k) * P^T (32k x 16q)
            bf16x8 pf = *(bf16x8*)(prow + 8 * g);
            bf16x8 vf = *(bf16x8*)(sm + VT_O + m * VT_S + kk0 + 8 * g);
            oacc = __builtin_amdgcn_mfma_f32_16x16x32_bf16(vf, pf, oacc, 0, 0, 0);
        }
    }

    // write per-query partials (no normalization here: key-split)
    int qg = bh * SS + hq * 64 + wq;
    float t1 = lsum + __shfl_xor(lsum, 16);
    float lf = t1 + __shfl_xor(t1, 32);
    if (g == 0) lq[kc * NQ + qg] = lf;
#pragma unroll
    for (int r = 0; r < 4; ++r)
        oq[((size_t)(kc * 16 + 4 * g + r)) * NQ + qg] = oacc[r];
}

// ---------------- Kernel 5: combine key-split partials, normalize, query-mean ----------------
__global__ __launch_bounds__(256) void k_red(const float* __restrict__ oq,
                                             const float* __restrict__ lq,
                                             float* __restrict__ acc) {
    int qg = blockIdx.x * 256 + threadIdx.x;
    int bh = qg >> 12;
    float inv = 1.f / (lq[qg] + lq[NQ + qg]);
#pragma unroll
    for (int d = 0; d < 16; ++d) {
        float val = (oq[(size_t)d * NQ + qg] + oq[(size_t)(16 + d) * NQ + qg]) * inv;
        val += __shfl_down(val, 32);
        val += __shfl_down(val, 16);
        val += __shfl_down(val, 8);
        val += __shfl_down(val, 4);
        val += __shfl_down(val, 2);
        val += __shfl_down(val, 1);
        if ((threadIdx.x & 63) == 0) atomicAdd(&acc[bh * DIM + d], val);
    }
}

// ---------------- Kernel 6: mean + out_proj + fc ----------------
__global__ __launch_bounds__(128) void k_head(const float* __restrict__ acc,
                                              const float* __restrict__ ow,
                                              const float* __restrict__ ob,
                                              const float* __restrict__ fw,
                                              const float* __restrict__ fb,
                                              float* __restrict__ out) {
    __shared__ float feat[2][64];
    int tid = threadIdx.x;
    int b = tid >> 6, c = tid & 63;
    float f2 = ob[c];
    const float invS = 1.f / (float)SS;
#pragma unroll
    for (int cc = 0; cc < 64; ++cc)
        f2 += (acc[b * 64 + cc] * invS) * ow[c * 64 + cc];
    feat[b][c] = f2;
    __syncthreads();
    if (tid < BB * NCLS) {
        int bb = tid >> 1, n = tid & 1;
        float r = fb[n];
#pragma unroll
        for (int cc = 0; cc < 64; ++cc) r += feat[bb][cc] * fw[n * 64 + cc];
        out[bb * NCLS + n] = r;
    }
}

extern "C" void kernel_launch(void* const* d_in, const int* in_sizes, int n_in,
                              void* d_out, int out_size, void* d_ws, size_t ws_size,
                              hipStream_t stream) {
    const float* x      = (const float*)d_in[0];
    const float* conv_w = (const float*)d_in[1];
    const float* conv_b = (const float*)d_in[2];
    const float* bn_g   = (const float*)d_in[3];
    const float* bn_b   = (const float*)d_in[4];
    const float* qkv_w  = (const float*)d_in[5];
    const float* qkv_b  = (const float*)d_in[6];
    const float* rph    = (const float*)d_in[7];
    const float* rpw    = (const float*)d_in[8];
    const float* out_w  = (const float*)d_in[9];
    const float* out_b  = (const float*)d_in[10];
    const float* fc_w   = (const float*)d_in[11];
    const float* fc_b   = (const float*)d_in[12];

    float* ws    = (float*)d_ws;
    float* y     = ws + Y_OFF;
    float* oq    = ws + OQ_OFF;
    float* lq    = ws + LQ_OFF;
    unsigned short* kbf = (unsigned short*)(ws + KBF_OFF);
    unsigned short* vT  = (unsigned short*)(ws + VTB_OFF);
    float* stats = ws + STAT_OFF;
    float* accb  = ws + ACC_OFF;
    float* t     = ws + T_OFF;
    float* q     = ws + Q_OFF;

    // zero stats (128) + attention accumulator (128)
    hipMemsetAsync(stats, 0, 256 * sizeof(float), stream);

    k_conv  <<<BB * HID * 4, 256, 0, stream>>>(x, conv_w, conv_b, y, stats);
    k_bnpool<<<BB * PP, 256, 0, stream>>>(y, stats, bn_g, bn_b, t);
    k_qkv   <<<(BB * SS) / 32, 256, 0, stream>>>(t, qkv_w, qkv_b, q, kbf, vT);
    k_attn  <<<BB * HEADS * PP * 2, 256, 0, stream>>>(q, kbf, vT, rph, rpw, oq, lq);
    k_red   <<<NQ / 256, 256, 0, stream>>>(oq, lq, accb);
    k_head  <<<1, 128, 0, stream>>>(accb, out_w, out_b, fc_w, fc_b, (float*)d_out);
}

// Round 6
// 143.633 us; speedup vs baseline: 10.2741x; 1.2809x over previous
//
#include <hip/hip_runtime.h>
#include <math.h>

#define BB 2
#define CIN 3
#define IMGD 128
#define HID 64
#define HEADS 4
#define DIM 16
#define PP 64
#define SS 4096
#define NCLS 2
#define EPSV 1e-5f
#define NQ 32768

// ws layout in floats
#define Y_OFF    0         // conv y (2,097,152); dead after bnqkv -> oq/lq overlay
#define OQ_OFF   0         // [32][NQ] = 1,048,576
#define LQ_OFF   1048576   // [2][NQ] = 65,536
#define KBF_OFF  1114112   // bf16 K [8][4096][16] -> 262,144 f32 slots
#define VTB_OFF  1376256   // bf16 V^T [8][16][4096] -> 262,144 f32 slots
#define STAT_OFF 2097152   // 128
#define ACC_OFF  2097280   // 128
#define Q_OFF    2097408   // q f32 (b,h,s,d) 524,288

typedef short bf16x8 __attribute__((ext_vector_type(8)));
typedef float f32x4 __attribute__((ext_vector_type(4)));

__device__ __forceinline__ unsigned short f2bf(float f) {
    unsigned int u = __float_as_uint(f);
    u += 0x7FFFu + ((u >> 16) & 1u);
    return (unsigned short)(u >> 16);
}
__device__ __forceinline__ unsigned int pk2(float lo, float hi) {
    return (unsigned int)f2bf(lo) | ((unsigned int)f2bf(hi) << 16);
}
__device__ __forceinline__ float dot16(const float* qf, float4 a0, float4 a1,
                                       float4 a2, float4 a3) {
    float s0 = qf[0] * a0.x + qf[1] * a0.y + qf[2] * a0.z + qf[3] * a0.w;
    float s1 = qf[4] * a1.x + qf[5] * a1.y + qf[6] * a1.z + qf[7] * a1.w;
    float s2 = qf[8] * a2.x + qf[9] * a2.y + qf[10] * a2.z + qf[11] * a2.w;
    float s3 = qf[12] * a3.x + qf[13] * a3.y + qf[14] * a3.z + qf[15] * a3.w;
    return (s0 + s1) + (s2 + s3);
}

// ---------------- Kernel 1: conv3x3 + bias + BN stats ----------------
__global__ __launch_bounds__(256) void k_conv(const float* __restrict__ x,
                                              const float* __restrict__ cw,
                                              const float* __restrict__ cb,
                                              float* __restrict__ y,
                                              float* __restrict__ stats) {
    int blk = blockIdx.x;
    int strip = blk & 3, c = (blk >> 2) & 63, b = blk >> 8;
    float w[27];
#pragma unroll
    for (int i = 0; i < 27; ++i) w[i] = cw[c * 27 + i];
    float bias = cb[c];
    const float* xb = x + b * CIN * IMGD * IMGD;
    float* yb = y + (b * HID + c) * IMGD * IMGD;
    float s1 = 0.f, s2 = 0.f;
    int base = strip * 4096;
#pragma unroll 4
    for (int ii = 0; ii < 16; ++ii) {
        int pix = base + ii * 256 + threadIdx.x;
        int h = pix >> 7, ww = pix & 127;
        float acc;
        if (h > 0 && h < 127 && ww > 0 && ww < 127) {
            float a0 = bias, a1 = 0.f, a2 = 0.f;
#pragma unroll
            for (int kh = 0; kh < 3; ++kh) {
#pragma unroll
                for (int kw = 0; kw < 3; ++kw) {
                    int off = (h + kh - 1) * IMGD + ww + kw - 1;
                    a0 += xb[off] * w[kh * 3 + kw];
                    a1 += xb[IMGD * IMGD + off] * w[9 + kh * 3 + kw];
                    a2 += xb[2 * IMGD * IMGD + off] * w[18 + kh * 3 + kw];
                }
            }
            acc = a0 + (a1 + a2);
        } else {
            acc = bias;
#pragma unroll
            for (int ci = 0; ci < 3; ++ci) {
                const float* xc = xb + ci * IMGD * IMGD;
#pragma unroll
                for (int kh = 0; kh < 3; ++kh) {
                    int hh = h + kh - 1;
                    if (hh < 0 || hh >= IMGD) continue;
#pragma unroll
                    for (int kw = 0; kw < 3; ++kw) {
                        int w2 = ww + kw - 1;
                        if (w2 < 0 || w2 >= IMGD) continue;
                        acc += xc[hh * IMGD + w2] * w[ci * 9 + kh * 3 + kw];
                    }
                }
            }
        }
        yb[pix] = acc;
        s1 += acc;
        s2 += acc * acc;
    }
    __shared__ float r1[256], r2[256];
    r1[threadIdx.x] = s1;
    r2[threadIdx.x] = s2;
    __syncthreads();
    for (int off = 128; off > 0; off >>= 1) {
        if (threadIdx.x < (unsigned)off) {
            r1[threadIdx.x] += r1[threadIdx.x + off];
            r2[threadIdx.x] += r2[threadIdx.x + off];
        }
        __syncthreads();
    }
    if (threadIdx.x == 0) {
        atomicAdd(&stats[c], r1[0]);
        atomicAdd(&stats[64 + c], r2[0]);
    }
}

// ---------------- Kernel 2: fused BN+ReLU+pool + qkv MFMA GEMM ----------------
// block = (b, ph, half): 64 s-rows x 96 n-cols. 4 waves.
#define TW_S 72
__global__ __launch_bounds__(256) void k_bnqkv(const float* __restrict__ y,
                                               const float* __restrict__ stats,
                                               const float* __restrict__ gamma,
                                               const float* __restrict__ beta,
                                               const float* __restrict__ qw,
                                               const float* __restrict__ qb,
                                               float* __restrict__ q,
                                               unsigned short* __restrict__ kbf,
                                               unsigned short* __restrict__ vT) {
    __shared__ unsigned short sm2[(64 + 96) * TW_S];
    unsigned short* lt = sm2;              // pooled tile [pw][c] bf16
    unsigned short* lw = sm2 + 64 * TW_S;  // weights [n_local][c] bf16
    int blk = blockIdx.x;
    int half = blk & 1, ph = (blk >> 1) & 63, b = blk >> 7;
    int tid = threadIdx.x;
    // stage weights (96 rows of this half)
    for (int idx = tid; idx < 96 * 16; idx += 256) {
        int nl = idx >> 4, c4 = (idx & 15) * 4;
        float4 wv = *(const float4*)(qw + (half * 96 + nl) * 64 + c4);
        *(uint2*)(lw + nl * TW_S + c4) = make_uint2(pk2(wv.x, wv.y), pk2(wv.z, wv.w));
    }
    // BN + relu + 2x2 maxpool -> lt
    const float invN = 1.f / (BB * IMGD * IMGD);
    for (int idx = tid; idx < 4096; idx += 256) {
        int c = idx >> 6, pw = idx & 63;
        float mu = stats[c] * invN;
        float var = stats[64 + c] * invN - mu * mu;
        float sc = rsqrtf(var + EPSV) * gamma[c];
        float sh = beta[c] - mu * sc;
        const float* yp = y + ((b * HID + c) * IMGD + 2 * ph) * IMGD + 2 * pw;
        float v0 = yp[0] * sc + sh;
        float v1 = yp[1] * sc + sh;
        float v2 = yp[IMGD] * sc + sh;
        float v3 = yp[IMGD + 1] * sc + sh;
        float mv = fmaxf(fmaxf(fmaxf(v0, v1), fmaxf(v2, v3)), 0.f);
        lt[pw * TW_S + c] = f2bf(mv);
    }
    __syncthreads();
    int w = tid >> 6, l = tid & 63, m = l & 15, g = l >> 4;
    f32x4 acc[6];
#pragma unroll
    for (int nt = 0; nt < 6; ++nt) {
        float bb = qb[half * 96 + nt * 16 + m];
        acc[nt] = (f32x4){bb, bb, bb, bb};
    }
#pragma unroll
    for (int ks = 0; ks < 2; ++ks) {
        // K-step offset is ks*32: each MFMA consumes 32 channels (g*8 spans 0..31)
        bf16x8 af = *(bf16x8*)(lt + (16 * w + m) * TW_S + ks * 32 + g * 8);
#pragma unroll
        for (int nt = 0; nt < 6; ++nt) {
            bf16x8 bf_ = *(bf16x8*)(lw + (nt * 16 + m) * TW_S + ks * 32 + g * 8);
            acc[nt] = __builtin_amdgcn_mfma_f32_16x16x32_bf16(af, bf_, acc[nt], 0, 0, 0);
        }
    }
#pragma unroll
    for (int nt = 0; nt < 6; ++nt) {
        int n = half * 96 + nt * 16 + m;
        int which = n >> 6, hh = (n >> 4) & 3, d = n & 15;  // d == m
        int bh = b * HEADS + hh;
#pragma unroll
        for (int r = 0; r < 4; ++r) {
            int s = ph * 64 + 16 * w + 4 * g + r;
            float val = acc[nt][r];
            if (which == 0)      q[((size_t)bh * SS + s) * DIM + d] = val;
            else if (which == 1) kbf[((size_t)bh * SS + s) * 16 + d] = f2bf(val);
            else                 vT[((size_t)bh * 16 + d) * SS + s] = f2bf(val);
        }
    }
}

// ---------------- Kernel 3: MFMA flash attention, bias fully in-MFMA ----------------
// LDS (u16 units), total 22528 B:
#define KK_O 0        // K~ [256][24]
#define RW_O 0        // overlay: rw table [64][72] bf16 (prologue->qfrag only)
#define V_O  6144     // V [16][256] swizzled 8B blocks
#define RH_O 10240    // rh2 f32 [32][16]
// rwF f32 [127][20] overlays V_O.. during prologue (rows>=103 clobbered by rh2 after last use)

__global__ __launch_bounds__(256, 4) void k_attn(const float* __restrict__ qbuf,
                                                 const unsigned short* __restrict__ kbf,
                                                 const unsigned short* __restrict__ vT,
                                                 const float* __restrict__ rph,
                                                 const float* __restrict__ rpw,
                                                 float* __restrict__ oq,
                                                 float* __restrict__ lq) {
    __shared__ unsigned short sm[11264];
    int blk = blockIdx.x;
    int kc = blk & 1;
    int hq = (blk >> 1) & 63;
    int bh = blk >> 7;
    int tid = threadIdx.x;
    int w = tid >> 6, l = tid & 63;
    int m = l & 15, g = l >> 4;
    int wq = w * 16 + m;

    // chunk-0 global loads issued early
    uint4 kr0, kr1, vr0, vr1;
    int vd = tid >> 4, vc = (tid & 15) * 16;
    {
        const uint4* kp = (const uint4*)(kbf + ((size_t)bh * SS + kc * 2048 + tid) * 16);
        kr0 = kp[0]; kr1 = kp[1];
        const uint4* vp = (const uint4*)(vT + ((size_t)bh * 16 + vd) * SS + kc * 2048 + vc);
        vr0 = vp[0]; vr1 = vp[1];
    }

    // prologue 1: stage Rw rows f32 [127][20]
    float* rwF = (float*)(sm + V_O);
    for (int i = tid; i < 127 * 16; i += 256) {
        int row = i >> 4, c = i & 15;
        rwF[row * 20 + c] = rpw[i];
    }
    __syncthreads();

    // prologue 2: rw table bf16 [64][72] (pre-scaled by log2 e)
    {
        int qq = tid & 63, part = tid >> 6;
        const float4* qp = (const float4*)(qbuf + ((size_t)bh * SS + hq * 64 + qq) * DIM);
        float qf[16];
        *(float4*)(qf) = qp[0]; *(float4*)(qf + 4) = qp[1];
        *(float4*)(qf + 8) = qp[2]; *(float4*)(qf + 12) = qp[3];
#pragma unroll
        for (int i = 0; i < 16; ++i) {
            int wk = part * 16 + i;
            const float4* rr = (const float4*)(rwF + (qq - wk + 63) * 20);
            float vv = dot16(qf, rr[0], rr[1], rr[2], rr[3]) * 1.44269504f;
            sm[RW_O + qq * 72 + wk] = f2bf(vv);
        }
    }
    __syncthreads();

    // prologue 3: rh2 f32 (pre-scaled) + fragment builds (rw region read here)
    float* rh2 = (float*)(sm + RH_O);
    for (int i = tid; i < 32 * 16; i += 256) {
        int hkl = i >> 4, c = i & 15;
        rh2[i] = rph[(hq + 63 - kc * 32 - hkl) * 16 + c] * 1.44269504f;
    }
    bf16x8 qv[4];
    if (g < 2) {
        const float* qrow = qbuf + ((size_t)bh * SS + hq * 64 + wq) * DIM + g * 8;
        float4 a = *(const float4*)(qrow);
        float4 b2 = *(const float4*)(qrow + 4);
        unsigned int u[4] = {pk2(a.x, a.y), pk2(a.z, a.w), pk2(b2.x, b2.y), pk2(b2.z, b2.w)};
        bf16x8 qp8 = *(bf16x8*)u;
        qv[0] = qv[1] = qv[2] = qv[3] = qp8;
    } else {
#pragma unroll
        for (int v2 = 0; v2 < 4; ++v2)
            qv[v2] = *(bf16x8*)(sm + RW_O + wq * 72 + v2 * 16 + (g - 2) * 8);
    }
    // delta A-frag for upper-K (constant per lane): A[m][16+m] = 1
    unsigned int dw[4];
    int act = (g == 2) ? (m < 8 ? m : -1) : ((g == 3) ? (m >= 8 ? m - 8 : -1) : -1);
#pragma unroll
    for (int i2 = 0; i2 < 4; ++i2)
        dw[i2] = (act >= 0 && (act >> 1) == i2) ? (0x3F80u << (16 * (act & 1))) : 0u;
    bf16x8 dfrag = *(bf16x8*)dw;
    unsigned int ow_[4] = {0x3F803F80u, 0x3F803F80u, 0x3F803F80u, 0x3F803F80u};
    bf16x8 ones = *(bf16x8*)ow_;
    __syncthreads();   // rw table + rwF dead; K/V regions free

    f32x4 oacc = {0.f, 0.f, 0.f, 0.f};
    f32x4 lacc = {0.f, 0.f, 0.f, 0.f};
    const float AC = 0.25f * 1.44269504f;

    for (int c = 0; c < 8; ++c) {
        // convert + write K~ = AC*K + rh2row ; write V (8B-block XOR swizzle)
        {
            const float* rr = rh2 + (c * 4 + (tid >> 6)) * 16;
            unsigned int kkp[8];
#pragma unroll
            for (int i = 0; i < 4; ++i) {
                unsigned int u = ((const unsigned int*)&kr0)[i];
                float lo = __uint_as_float(u << 16);
                float hi = __uint_as_float(u & 0xffff0000u);
                float f0 = fmaf(lo, AC, rr[2 * i]);
                float f1 = fmaf(hi, AC, rr[2 * i + 1]);
                kkp[i] = pk2(f0, f1);
            }
#pragma unroll
            for (int i = 0; i < 4; ++i) {
                unsigned int u = ((const unsigned int*)&kr1)[i];
                float lo = __uint_as_float(u << 16);
                float hi = __uint_as_float(u & 0xffff0000u);
                float f0 = fmaf(lo, AC, rr[8 + 2 * i]);
                float f1 = fmaf(hi, AC, rr[9 + 2 * i]);
                kkp[4 + i] = pk2(f0, f1);
            }
            *(uint4*)(sm + KK_O + tid * 24) = *(uint4*)kkp;
            *(uint4*)(sm + KK_O + tid * 24 + 8) = *(uint4*)(kkp + 4);
            int r7 = vd & 7, bb0 = vc >> 2;
            *(uint2*)(sm + V_O + vd * 256 + ((bb0 + 0) ^ r7) * 4) = make_uint2(vr0.x, vr0.y);
            *(uint2*)(sm + V_O + vd * 256 + ((bb0 + 1) ^ r7) * 4) = make_uint2(vr0.z, vr0.w);
            *(uint2*)(sm + V_O + vd * 256 + ((bb0 + 2) ^ r7) * 4) = make_uint2(vr1.x, vr1.y);
            *(uint2*)(sm + V_O + vd * 256 + ((bb0 + 3) ^ r7) * 4) = make_uint2(vr1.z, vr1.w);
        }
        __syncthreads();
        if (c < 7) {
            const uint4* kp = (const uint4*)(kbf + ((size_t)bh * SS + kc * 2048 + (c + 1) * 256 + tid) * 16);
            kr0 = kp[0]; kr1 = kp[1];
            const uint4* vp = (const uint4*)(vT + ((size_t)bh * 16 + vd) * SS + kc * 2048 + (c + 1) * 256 + vc);
            vr0 = vp[0]; vr1 = vp[1];
        }

#pragma unroll
        for (int g2 = 0; g2 < 8; ++g2) {
            const int kk0 = g2 * 32;
            unsigned int pp[4];
#pragma unroll
            for (int t2 = 0; t2 < 2; ++t2) {
                bf16x8 kf = dfrag;
                if (g < 2)
                    kf = *(bf16x8*)(sm + KK_O + (kk0 + t2 * 16 + m) * 24 + g * 8);
                f32x4 st = __builtin_amdgcn_mfma_f32_16x16x32_bf16(
                    kf, qv[(g2 & 1) * 2 + t2], (f32x4){0.f, 0.f, 0.f, 0.f}, 0, 0, 0);
                float p0 = __builtin_exp2f(st[0]);
                float p1 = __builtin_exp2f(st[1]);
                float p2 = __builtin_exp2f(st[2]);
                float p3 = __builtin_exp2f(st[3]);
                unsigned int u0, u1;
                asm("v_cvt_pk_bf16_f32 %0, %1, %2" : "=v"(u0) : "v"(p0), "v"(p1));
                asm("v_cvt_pk_bf16_f32 %0, %1, %2" : "=v"(u1) : "v"(p2), "v"(p3));
                pp[2 * t2] = u0;
                pp[2 * t2 + 1] = u1;
            }
            bf16x8 pfrag = *(bf16x8*)pp;
            int r7 = m & 7;
            uint2 va = *(uint2*)(sm + V_O + m * 256 + ((8 * g2 + g) ^ r7) * 4);
            uint2 vb = *(uint2*)(sm + V_O + m * 256 + ((8 * g2 + 4 + g) ^ r7) * 4);
            unsigned int vv[4] = {va.x, va.y, vb.x, vb.y};
            bf16x8 vf = *(bf16x8*)vv;
            oacc = __builtin_amdgcn_mfma_f32_16x16x32_bf16(vf, pfrag, oacc, 0, 0, 0);
            lacc = __builtin_amdgcn_mfma_f32_16x16x32_bf16(ones, pfrag, lacc, 0, 0, 0);
        }
        __syncthreads();
    }

    int qg = bh * SS + hq * 64 + wq;
    if (g == 0) lq[kc * NQ + qg] = lacc[0];
#pragma unroll
    for (int r = 0; r < 4; ++r)
        oq[((size_t)(kc * 16 + 4 * g + r)) * NQ + qg] = oacc[r];
}

// ---------------- Kernel 4: combine key-split partials, normalize, query-mean ----------------
__global__ __launch_bounds__(256) void k_red(const float* __restrict__ oq,
                                             const float* __restrict__ lq,
                                             float* __restrict__ acc) {
    int qg = blockIdx.x * 256 + threadIdx.x;
    int bh = qg >> 12;
    float inv = 1.f / (lq[qg] + lq[NQ + qg]);
#pragma unroll
    for (int d = 0; d < 16; ++d) {
        float val = (oq[(size_t)d * NQ + qg] + oq[(size_t)(16 + d) * NQ + qg]) * inv;
        val += __shfl_down(val, 32);
        val += __shfl_down(val, 16);
        val += __shfl_down(val, 8);
        val += __shfl_down(val, 4);
        val += __shfl_down(val, 2);
        val += __shfl_down(val, 1);
        if ((threadIdx.x & 63) == 0) atomicAdd(&acc[bh * DIM + d], val);
    }
}

// ---------------- Kernel 5: mean + out_proj + fc ----------------
__global__ __launch_bounds__(128) void k_head(const float* __restrict__ acc,
                                              const float* __restrict__ ow,
                                              const float* __restrict__ ob,
                                              const float* __restrict__ fw,
                                              const float* __restrict__ fb,
                                              float* __restrict__ out) {
    __shared__ float feat[2][64];
    int tid = threadIdx.x;
    int b = tid >> 6, c = tid & 63;
    float f2 = ob[c];
    const float invS = 1.f / (float)SS;
#pragma unroll
    for (int cc = 0; cc < 64; ++cc)
        f2 += (acc[b * 64 + cc] * invS) * ow[c * 64 + cc];
    feat[b][c] = f2;
    __syncthreads();
    if (tid < BB * NCLS) {
        int bb = tid >> 1, n = tid & 1;
        float r = fb[n];
#pragma unroll
        for (int cc = 0; cc < 64; ++cc) r += feat[bb][cc] * fw[n * 64 + cc];
        out[bb * NCLS + n] = r;
    }
}

extern "C" void kernel_launch(void* const* d_in, const int* in_sizes, int n_in,
                              void* d_out, int out_size, void* d_ws, size_t ws_size,
                              hipStream_t stream) {
    const float* x      = (const float*)d_in[0];
    const float* conv_w = (const float*)d_in[1];
    const float* conv_b = (const float*)d_in[2];
    const float* bn_g   = (const float*)d_in[3];
    const float* bn_b   = (const float*)d_in[4];
    const float* qkv_w  = (const float*)d_in[5];
    const float* qkv_b  = (const float*)d_in[6];
    const float* rph    = (const float*)d_in[7];
    const float* rpw    = (const float*)d_in[8];
    const float* out_w  = (const float*)d_in[9];
    const float* out_b  = (const float*)d_in[10];
    const float* fc_w   = (const float*)d_in[11];
    const float* fc_b   = (const float*)d_in[12];

    float* ws    = (float*)d_ws;
    float* y     = ws + Y_OFF;
    float* oq    = ws + OQ_OFF;
    float* lq    = ws + LQ_OFF;
    unsigned short* kbf = (unsigned short*)(ws + KBF_OFF);
    unsigned short* vT  = (unsigned short*)(ws + VTB_OFF);
    float* stats = ws + STAT_OFF;
    float* accb  = ws + ACC_OFF;
    float* q     = ws + Q_OFF;

    hipMemsetAsync(stats, 0, 256 * sizeof(float), stream);

    k_conv  <<<BB * HID * 4, 256, 0, stream>>>(x, conv_w, conv_b, y, stats);
    k_bnqkv <<<BB * PP * 2, 256, 0, stream>>>(y, stats, bn_g, bn_b, qkv_w, qkv_b, q, kbf, vT);
    k_attn  <<<BB * HEADS * PP * 2, 256, 0, stream>>>(q, kbf, vT, rph, rpw, oq, lq);
    k_red   <<<NQ / 256, 256, 0, stream>>>(oq, lq, accb);
    k_head  <<<1, 128, 0, stream>>>(accb, out_w, out_b, fc_w, fc_b, (float*)d_out);
}

// Round 7
// 128.609 us; speedup vs baseline: 11.4743x; 1.1168x over previous
//
#include <hip/hip_runtime.h>
#include <math.h>

#define BB 2
#define CIN 3
#define IMGD 128
#define HID 64
#define HEADS 4
#define DIM 16
#define PP 64
#define SS 4096
#define NCLS 2
#define EPSV 1e-5f
#define NQ 32768

// ws layout in floats
#define OQ_OFF   0         // [16][NQ] = 524,288 (atomic partials)
#define LQ_OFF   524288    // [NQ] = 32,768
#define P_OFF    557056    // pooled conv pre-BN [2][64][64][64] = 524,288
#define KBF_OFF  1114112   // bf16 K [8][4096][16] -> 262,144 f32 slots
#define VTB_OFF  1376256   // bf16 V^T [8][16][4096] -> 262,144 f32 slots
#define STAT_OFF 2097152   // 128
#define ACC_OFF  2097280   // 128
#define Q_OFF    2097408   // q f32 (b,h,s,d) 524,288

typedef short bf16x8 __attribute__((ext_vector_type(8)));
typedef float f32x4 __attribute__((ext_vector_type(4)));

__device__ __forceinline__ unsigned short f2bf(float f) {
    unsigned int u = __float_as_uint(f);
    u += 0x7FFFu + ((u >> 16) & 1u);
    return (unsigned short)(u >> 16);
}
__device__ __forceinline__ unsigned int pk2(float lo, float hi) {
    return (unsigned int)f2bf(lo) | ((unsigned int)f2bf(hi) << 16);
}
__device__ __forceinline__ float dot16(const float* qf, float4 a0, float4 a1,
                                       float4 a2, float4 a3) {
    float s0 = qf[0] * a0.x + qf[1] * a0.y + qf[2] * a0.z + qf[3] * a0.w;
    float s1 = qf[4] * a1.x + qf[5] * a1.y + qf[6] * a1.z + qf[7] * a1.w;
    float s2 = qf[8] * a2.x + qf[9] * a2.y + qf[10] * a2.z + qf[11] * a2.w;
    float s3 = qf[12] * a3.x + qf[13] * a3.y + qf[14] * a3.z + qf[15] * a3.w;
    return (s0 + s1) + (s2 + s3);
}

// ---------------- Kernel 1: conv3x3 + bias + BN stats + raw 2x2 maxpool ----------------
// grid (b, ph, cq): 512 blocks. thread = (c = tid>>2, q = tid&3): 2 rows x 8 cols.
// Pool commutes with BN+ReLU because BN scale (gamma=1) > 0; stats over full-res.
__global__ __launch_bounds__(256, 4) void k_conv(const float* __restrict__ x,
                                                 const float* __restrict__ cw,
                                                 const float* __restrict__ cb,
                                                 float* __restrict__ P,
                                                 float* __restrict__ stats) {
    int blk = blockIdx.x;
    int cq = blk & 3, ph = (blk >> 2) & 63, b = blk >> 8;
    __shared__ float xl[3][4][36];
    int tid = threadIdx.x;
    for (int i = tid; i < 3 * 4 * 36; i += 256) {
        int ch = i / 144, rem = i % 144, row = rem / 36, col = rem % 36;
        int h = 2 * ph - 1 + row, gc = cq * 32 - 1 + col;
        float v = 0.f;
        if (h >= 0 && h < IMGD && gc >= 0 && gc < IMGD && col < 34)
            v = x[((b * 3 + ch) * IMGD + h) * IMGD + gc];
        xl[ch][row][col] = v;
    }
    __syncthreads();
    int c = tid >> 2, q = tid & 3;
    float w[27];
#pragma unroll
    for (int i = 0; i < 27; ++i) w[i] = cw[c * 27 + i];
    float bias = cb[c];
    float a0[8], a1[8];
#pragma unroll
    for (int j = 0; j < 8; ++j) { a0[j] = bias; a1[j] = bias; }
#pragma unroll
    for (int ch = 0; ch < 3; ++ch) {
        float rv[4][10];
#pragma unroll
        for (int rr = 0; rr < 4; ++rr)
#pragma unroll
            for (int t = 0; t < 10; ++t) rv[rr][t] = xl[ch][rr][q * 8 + t];
#pragma unroll
        for (int kh = 0; kh < 3; ++kh) {
            float w0 = w[ch * 9 + kh * 3], w1 = w[ch * 9 + kh * 3 + 1], w2 = w[ch * 9 + kh * 3 + 2];
#pragma unroll
            for (int j = 0; j < 8; ++j) {
                a0[j] += rv[kh][j] * w0 + rv[kh][j + 1] * w1 + rv[kh][j + 2] * w2;
                a1[j] += rv[kh + 1][j] * w0 + rv[kh + 1][j + 1] * w1 + rv[kh + 1][j + 2] * w2;
            }
        }
    }
    float s1 = 0.f, s2 = 0.f;
#pragma unroll
    for (int j = 0; j < 8; ++j) {
        s1 += a0[j] + a1[j];
        s2 += a0[j] * a0[j] + a1[j] * a1[j];
    }
    s1 += __shfl_xor(s1, 1); s1 += __shfl_xor(s1, 2);
    s2 += __shfl_xor(s2, 1); s2 += __shfl_xor(s2, 2);
    if (q == 0) {
        atomicAdd(&stats[c], s1);
        atomicAdd(&stats[64 + c], s2);
    }
    float4 pv;
    float* pvf = (float*)&pv;
#pragma unroll
    for (int j4 = 0; j4 < 4; ++j4)
        pvf[j4] = fmaxf(fmaxf(a0[2 * j4], a0[2 * j4 + 1]), fmaxf(a1[2 * j4], a1[2 * j4 + 1]));
    *(float4*)(P + ((size_t)((b * 64 + c) * 64 + ph)) * 64 + cq * 16 + q * 4) = pv;
}

// ---------------- Kernel 2: fused BN+ReLU (on pooled) + qkv MFMA GEMM ----------------
#define TW_S 72
__global__ __launch_bounds__(256) void k_bnqkv(const float* __restrict__ P,
                                               const float* __restrict__ stats,
                                               const float* __restrict__ gamma,
                                               const float* __restrict__ beta,
                                               const float* __restrict__ qw,
                                               const float* __restrict__ qb,
                                               float* __restrict__ q,
                                               unsigned short* __restrict__ kbf,
                                               unsigned short* __restrict__ vT) {
    __shared__ unsigned short sm2[(64 + 96) * TW_S];
    unsigned short* lt = sm2;
    unsigned short* lw = sm2 + 64 * TW_S;
    int blk = blockIdx.x;
    int half = blk & 1, ph = (blk >> 1) & 63, b = blk >> 7;
    int tid = threadIdx.x;
    for (int idx = tid; idx < 96 * 16; idx += 256) {
        int nl = idx >> 4, c4 = (idx & 15) * 4;
        float4 wv = *(const float4*)(qw + (half * 96 + nl) * 64 + c4);
        *(uint2*)(lw + nl * TW_S + c4) = make_uint2(pk2(wv.x, wv.y), pk2(wv.z, wv.w));
    }
    const float invN = 1.f / (BB * IMGD * IMGD);
    for (int idx = tid; idx < 4096; idx += 256) {
        int c = idx >> 6, pw = idx & 63;
        float mu = stats[c] * invN;
        float var = stats[64 + c] * invN - mu * mu;
        float sc = rsqrtf(var + EPSV) * gamma[c];
        float sh = beta[c] - mu * sc;
        float mv = fmaxf(P[((size_t)((b * 64 + c) * 64 + ph)) * 64 + pw] * sc + sh, 0.f);
        lt[pw * TW_S + c] = f2bf(mv);
    }
    __syncthreads();
    int w = tid >> 6, l = tid & 63, m = l & 15, g = l >> 4;
    f32x4 acc[6];
#pragma unroll
    for (int nt = 0; nt < 6; ++nt) {
        float bb = qb[half * 96 + nt * 16 + m];
        acc[nt] = (f32x4){bb, bb, bb, bb};
    }
#pragma unroll
    for (int ks = 0; ks < 2; ++ks) {
        bf16x8 af = *(bf16x8*)(lt + (16 * w + m) * TW_S + ks * 32 + g * 8);
#pragma unroll
        for (int nt = 0; nt < 6; ++nt) {
            bf16x8 bf_ = *(bf16x8*)(lw + (nt * 16 + m) * TW_S + ks * 32 + g * 8);
            acc[nt] = __builtin_amdgcn_mfma_f32_16x16x32_bf16(af, bf_, acc[nt], 0, 0, 0);
        }
    }
#pragma unroll
    for (int nt = 0; nt < 6; ++nt) {
        int n = half * 96 + nt * 16 + m;
        int which = n >> 6, hh = (n >> 4) & 3, d = n & 15;
        int bh = b * HEADS + hh;
#pragma unroll
        for (int r = 0; r < 4; ++r) {
            int s = ph * 64 + 16 * w + 4 * g + r;
            float val = acc[nt][r];
            if (which == 0)      q[((size_t)bh * SS + s) * DIM + d] = val;
            else if (which == 1) kbf[((size_t)bh * SS + s) * 16 + d] = f2bf(val);
            else                 vT[((size_t)bh * 16 + d) * SS + s] = f2bf(val);
        }
    }
}

// ---------------- Kernel 3: MFMA flash attention, hq-pair 8-wave blocks, kc x4 ----------------
// LDS u16 layout (total 17408 u16 = 34816 B):
#define KK_O 0        // K~ 2 bufs x [256][24]  (buf stride 6144)
#define RW_O 0        // prologue overlay: rw table [128][72]
#define V_O  12288    // V [16][256] swizzled 8B blocks
#define RH_O 16384    // rh2 f32 [2][16][16]
// rwF f32 [127][20] overlays V_O.. during prologue phases 1-2

__global__ __launch_bounds__(512, 6) void k_attn(const float* __restrict__ qbuf,
                                                 const unsigned short* __restrict__ kbf,
                                                 const unsigned short* __restrict__ vT,
                                                 const float* __restrict__ rph,
                                                 const float* __restrict__ rpw,
                                                 float* __restrict__ oq,
                                                 float* __restrict__ lq) {
    __shared__ unsigned short sm[17408];
    int blk = blockIdx.x;
    int kc = blk & 3;
    int hp = (blk >> 2) & 31;
    int bh = blk >> 7;
    int tid = threadIdx.x;
    int w = tid >> 6, l = tid & 63;
    int m = l & 15, g = l >> 4;
    int wq = (w & 3) * 16 + m;
    int hq = 2 * hp + (w >> 2);
    const float AC = 0.25f * 1.44269504f;

    // chunk-0 global loads issued early (hidden under prologue)
    uint4 kr0, kr1, vr0;
    int key = tid & 255, kbuf = tid >> 8;
    int vd = tid & 15, vkg = (tid >> 4) & 31;
    {
        const uint4* kp = (const uint4*)(kbf + ((size_t)bh * SS + kc * 1024 + key) * 16);
        kr0 = kp[0]; kr1 = kp[1];
        vr0 = *(const uint4*)(vT + ((size_t)bh * 16 + vd) * SS + kc * 1024 + vkg * 8);
    }

    // phase 1: stage Rw rows f32 [127][20]
    float* rwF = (float*)(sm + V_O);
    for (int i = tid; i < 127 * 16; i += 512) {
        int row = i >> 4, cc = i & 15;
        rwF[row * 20 + cc] = rpw[i];
    }
    __syncthreads();

    // phase 2: rw table bf16 [128][72] (pre-scaled by log2 e)
    {
        int qq = tid & 127, part = tid >> 7;
        int hl = qq >> 6, qql = qq & 63;
        const float4* qp = (const float4*)(qbuf + ((size_t)bh * SS + (2 * hp + hl) * 64 + qql) * DIM);
        float qf[16];
        *(float4*)(qf) = qp[0]; *(float4*)(qf + 4) = qp[1];
        *(float4*)(qf + 8) = qp[2]; *(float4*)(qf + 12) = qp[3];
#pragma unroll
        for (int i = 0; i < 16; ++i) {
            int wk = part * 16 + i;
            const float4* rr = (const float4*)(rwF + (qql - wk + 63) * 20);
            float vv = dot16(qf, rr[0], rr[1], rr[2], rr[3]) * 1.44269504f;
            sm[RW_O + qq * 72 + wk] = f2bf(vv);
        }
    }
    __syncthreads();

    // phase 3: rh2 fill (clobbers rwF tail - dead) + fragment builds (read rw table)
    float* rhF = (float*)(sm + RH_O);
    {
        int i = tid;   // 512 entries, 512 threads
        if (i < 512) {
            int hl = i >> 8, hkl = (i >> 4) & 15, cc = i & 15;
            rhF[i] = rph[(2 * hp + hl + 63 - (kc * 16 + hkl)) * 16 + cc] * 1.44269504f;
        }
    }
    bf16x8 qv[4];
    if (g < 2) {
        const float* qrow = qbuf + ((size_t)bh * SS + hq * 64 + wq) * DIM + g * 8;
        float4 a = *(const float4*)(qrow);
        float4 b2 = *(const float4*)(qrow + 4);
        unsigned int u[4] = {pk2(a.x, a.y), pk2(a.z, a.w), pk2(b2.x, b2.y), pk2(b2.z, b2.w)};
        bf16x8 qp8 = *(bf16x8*)u;
        qv[0] = qv[1] = qv[2] = qv[3] = qp8;
    } else {
        int qq = (w >> 2) * 64 + wq;
#pragma unroll
        for (int v2 = 0; v2 < 4; ++v2)
            qv[v2] = *(bf16x8*)(sm + RW_O + qq * 72 + v2 * 16 + (g - 2) * 8);
    }
    unsigned int dw[4];
    int act = (g == 2) ? (m < 8 ? m : -1) : ((g == 3) ? (m >= 8 ? m - 8 : -1) : -1);
#pragma unroll
    for (int i2 = 0; i2 < 4; ++i2)
        dw[i2] = (act >= 0 && (act >> 1) == i2) ? (0x3F80u << (16 * (act & 1))) : 0u;
    bf16x8 dfrag = *(bf16x8*)dw;
    unsigned int ow_[4] = {0x3F803F80u, 0x3F803F80u, 0x3F803F80u, 0x3F803F80u};
    bf16x8 ones = *(bf16x8*)ow_;
    __syncthreads();   // rw table + rwF dead; KK/V free for staging

    f32x4 oacc = {0.f, 0.f, 0.f, 0.f};
    f32x4 lacc = {0.f, 0.f, 0.f, 0.f};
    const int kbase = KK_O + (w >> 2) * 6144;

    for (int c = 0; c < 4; ++c) {
        // stage: K~ = AC*K + rh2[buf] row (rh fold per hq), V 8B-block swizzle
        {
            const float* rr = rhF + (kbuf * 16 + (c << 2) + (key >> 6)) * 16;
            unsigned int kkp[8];
            const unsigned int* kru = (const unsigned int*)&kr0;
#pragma unroll
            for (int i = 0; i < 4; ++i) {
                float lo = __uint_as_float(kru[i] << 16);
                float hi = __uint_as_float(kru[i] & 0xffff0000u);
                float f0 = fmaf(lo, AC, rr[2 * i]);
                float f1 = fmaf(hi, AC, rr[2 * i + 1]);
                asm("v_cvt_pk_bf16_f32 %0, %1, %2" : "=v"(kkp[i]) : "v"(f0), "v"(f1));
            }
            const unsigned int* kru1 = (const unsigned int*)&kr1;
#pragma unroll
            for (int i = 0; i < 4; ++i) {
                float lo = __uint_as_float(kru1[i] << 16);
                float hi = __uint_as_float(kru1[i] & 0xffff0000u);
                float f0 = fmaf(lo, AC, rr[8 + 2 * i]);
                float f1 = fmaf(hi, AC, rr[9 + 2 * i]);
                asm("v_cvt_pk_bf16_f32 %0, %1, %2" : "=v"(kkp[4 + i]) : "v"(f0), "v"(f1));
            }
            *(uint4*)(sm + kbuf * 6144 + key * 24) = *(uint4*)kkp;
            *(uint4*)(sm + kbuf * 6144 + key * 24 + 8) = *(uint4*)(kkp + 4);
            unsigned short* vbase = sm + V_O + vd * 256;
            int r7 = vd & 7;
            *(uint2*)(vbase + (((vkg * 2 + 0) ^ r7) << 2)) = make_uint2(vr0.x, vr0.y);
            *(uint2*)(vbase + (((vkg * 2 + 1) ^ r7) << 2)) = make_uint2(vr0.z, vr0.w);
        }
        __syncthreads();
        if (c < 3) {
            const uint4* kp = (const uint4*)(kbf + ((size_t)bh * SS + kc * 1024 + (c + 1) * 256 + key) * 16);
            kr0 = kp[0]; kr1 = kp[1];
            vr0 = *(const uint4*)(vT + ((size_t)bh * 16 + vd) * SS + kc * 1024 + (c + 1) * 256 + vkg * 8);
        }

#pragma unroll
        for (int g2 = 0; g2 < 8; ++g2) {
            const int kk0 = g2 * 32;
            unsigned int pp[4];
#pragma unroll
            for (int t2 = 0; t2 < 2; ++t2) {
                bf16x8 kf = dfrag;
                if (g < 2)
                    kf = *(bf16x8*)(sm + kbase + (kk0 + t2 * 16 + m) * 24 + g * 8);
                f32x4 st = __builtin_amdgcn_mfma_f32_16x16x32_bf16(
                    kf, qv[(g2 & 1) * 2 + t2], (f32x4){0.f, 0.f, 0.f, 0.f}, 0, 0, 0);
                float p0 = __builtin_exp2f(st[0]);
                float p1 = __builtin_exp2f(st[1]);
                float p2 = __builtin_exp2f(st[2]);
                float p3 = __builtin_exp2f(st[3]);
                unsigned int u0, u1;
                asm("v_cvt_pk_bf16_f32 %0, %1, %2" : "=v"(u0) : "v"(p0), "v"(p1));
                asm("v_cvt_pk_bf16_f32 %0, %1, %2" : "=v"(u1) : "v"(p2), "v"(p3));
                pp[2 * t2] = u0;
                pp[2 * t2 + 1] = u1;
            }
            bf16x8 pfrag = *(bf16x8*)pp;
            int r7 = m & 7;
            uint2 va = *(uint2*)(sm + V_O + m * 256 + (((8 * g2 + g) ^ r7) << 2));
            uint2 vb = *(uint2*)(sm + V_O + m * 256 + (((8 * g2 + 4 + g) ^ r7) << 2));
            unsigned int vv[4] = {va.x, va.y, vb.x, vb.y};
            bf16x8 vf = *(bf16x8*)vv;
            oacc = __builtin_amdgcn_mfma_f32_16x16x32_bf16(vf, pfrag, oacc, 0, 0, 0);
            lacc = __builtin_amdgcn_mfma_f32_16x16x32_bf16(ones, pfrag, lacc, 0, 0, 0);
        }
        __syncthreads();
    }

    int qg = bh * SS + hq * 64 + wq;
    if (g == 0) atomicAdd(&lq[qg], lacc[0]);
#pragma unroll
    for (int r = 0; r < 4; ++r)
        atomicAdd(&oq[((size_t)(4 * g + r)) * NQ + qg], oacc[r]);
}

// ---------------- Kernel 4: normalize + query-mean ----------------
__global__ __launch_bounds__(256) void k_red(const float* __restrict__ oq,
                                             const float* __restrict__ lq,
                                             float* __restrict__ acc) {
    int qg = blockIdx.x * 256 + threadIdx.x;
    int bh = qg >> 12;
    float inv = 1.f / lq[qg];
#pragma unroll
    for (int d = 0; d < 16; ++d) {
        float val = oq[(size_t)d * NQ + qg] * inv;
        val += __shfl_down(val, 32);
        val += __shfl_down(val, 16);
        val += __shfl_down(val, 8);
        val += __shfl_down(val, 4);
        val += __shfl_down(val, 2);
        val += __shfl_down(val, 1);
        if ((threadIdx.x & 63) == 0) atomicAdd(&acc[bh * DIM + d], val);
    }
}

// ---------------- Kernel 5: mean + out_proj + fc ----------------
__global__ __launch_bounds__(128) void k_head(const float* __restrict__ acc,
                                              const float* __restrict__ ow,
                                              const float* __restrict__ ob,
                                              const float* __restrict__ fw,
                                              const float* __restrict__ fb,
                                              float* __restrict__ out) {
    __shared__ float feat[2][64];
    int tid = threadIdx.x;
    int b = tid >> 6, c = tid & 63;
    float f2 = ob[c];
    const float invS = 1.f / (float)SS;
#pragma unroll
    for (int cc = 0; cc < 64; ++cc)
        f2 += (acc[b * 64 + cc] * invS) * ow[c * 64 + cc];
    feat[b][c] = f2;
    __syncthreads();
    if (tid < BB * NCLS) {
        int bb = tid >> 1, n = tid & 1;
        float r = fb[n];
#pragma unroll
        for (int cc = 0; cc < 64; ++cc) r += feat[bb][cc] * fw[n * 64 + cc];
        out[bb * NCLS + n] = r;
    }
}

extern "C" void kernel_launch(void* const* d_in, const int* in_sizes, int n_in,
                              void* d_out, int out_size, void* d_ws, size_t ws_size,
                              hipStream_t stream) {
    const float* x      = (const float*)d_in[0];
    const float* conv_w = (const float*)d_in[1];
    const float* conv_b = (const float*)d_in[2];
    const float* bn_g   = (const float*)d_in[3];
    const float* bn_b   = (const float*)d_in[4];
    const float* qkv_w  = (const float*)d_in[5];
    const float* qkv_b  = (const float*)d_in[6];
    const float* rph    = (const float*)d_in[7];
    const float* rpw    = (const float*)d_in[8];
    const float* out_w  = (const float*)d_in[9];
    const float* out_b  = (const float*)d_in[10];
    const float* fc_w   = (const float*)d_in[11];
    const float* fc_b   = (const float*)d_in[12];

    float* ws    = (float*)d_ws;
    float* oq    = ws + OQ_OFF;
    float* lq    = ws + LQ_OFF;
    float* P     = ws + P_OFF;
    unsigned short* kbf = (unsigned short*)(ws + KBF_OFF);
    unsigned short* vT  = (unsigned short*)(ws + VTB_OFF);
    float* stats = ws + STAT_OFF;
    float* accb  = ws + ACC_OFF;
    float* q     = ws + Q_OFF;

    // zero stats(128)+acc(128), and oq+lq partial buffers
    hipMemsetAsync(stats, 0, 256 * sizeof(float), stream);
    hipMemsetAsync(oq, 0, (16 * NQ + NQ) * sizeof(float), stream);

    k_conv  <<<BB * PP * 4, 256, 0, stream>>>(x, conv_w, conv_b, P, stats);
    k_bnqkv <<<BB * PP * 2, 256, 0, stream>>>(P, stats, bn_g, bn_b, qkv_w, qkv_b, q, kbf, vT);
    k_attn  <<<BB * HEADS * 32 * 4, 512, 0, stream>>>(q, kbf, vT, rph, rpw, oq, lq);
    k_red   <<<NQ / 256, 256, 0, stream>>>(oq, lq, accb);
    k_head  <<<1, 128, 0, stream>>>(accb, out_w, out_b, fc_w, fc_b, (float*)d_out);
}